// Round 6
// baseline (2116.765 us; speedup 1.0000x reference)
//
#include <hip/hip_runtime.h>
#include <hip/hip_bf16.h>
#include <stdint.h>

// Dims: T=4, B=16, C=512, N=256 (16x16). heads=8, d=64. groups g = t*16+b (64).
#define BCN  (16*512*256)
#define CN   (512*256)
#define NG   64
#define CAP  65536

typedef __attribute__((ext_vector_type(8))) short bf16x8;
typedef __attribute__((ext_vector_type(4))) float f32x4;
typedef __attribute__((ext_vector_type(4))) int   int4v;
typedef unsigned char u8;

__device__ inline ushort f2bf(float x){ union{ __hip_bfloat16 b; ushort u; } z; z.b = __float2bfloat16(x); return z.u; }
__device__ inline float  bf2f(ushort u){ union{ uint i; float f; } z; z.i = (uint)u<<16; return z.f; }

__device__ inline double blk_reduce(double v, double* sh){
  int tid = threadIdx.x; sh[tid] = v; __syncthreads();
  for (int off=128; off>0; off>>=1){ if (tid<off) sh[tid]+=sh[tid+off]; __syncthreads(); }
  double r = sh[0]; __syncthreads(); return r;
}

// ---------------------------------------------------------------------------
__global__ __launch_bounds__(256) void guard_fill(float* out, int n){
  int i = blockIdx.x*256+threadIdx.x; if (i<n) out[i] = -1.0f;
}

// W (f32 [o][c]) -> Whi/Wlo bf16 [o][c]
__global__ __launch_bounds__(256) void w_split(const float* __restrict__ W,
                                               ushort* __restrict__ Whi, ushort* __restrict__ Wlo){
  int i = blockIdx.x*256+threadIdx.x; if (i >= 512*512) return;
  float x = W[i]; ushort h = f2bf(x);
  Whi[i] = h; Wlo[i] = f2bf(x - bf2f(h));
}

// ||W[o,:]||_2 fp64
__global__ __launch_bounds__(256) void wnorm_k(const float* __restrict__ W, double* __restrict__ wn){
  __shared__ double sh[256];
  int o = blockIdx.x;
  double s = 0.0;
  for (int c = threadIdx.x; c < 512; c += 256){ double w = (double)W[o*512+c]; s += w*w; }
  double t = blk_reduce(s, sh);
  if (threadIdx.x==0) wn[o] = sqrt(t);
}

// X [g][c][n] f32 -> XT32 [g][n][c] f32   (64x64 tiles)
__global__ __launch_bounds__(256) void xtrans32(const float* __restrict__ X, float* __restrict__ XT){
  __shared__ float lds[64][65];
  const int g = blockIdx.z, c0 = blockIdx.y<<6, n0 = blockIdx.x<<6;
  const int t = threadIdx.x, r = t>>2, q = t&3;
  #pragma unroll
  for (int u4=0; u4<4; ++u4){
    f32x4 v = *(const f32x4*)&X[((size_t)g*512 + c0 + r)*256 + n0 + q*16 + u4*4];
    lds[r][q*16+u4*4+0]=v.x; lds[r][q*16+u4*4+1]=v.y; lds[r][q*16+u4*4+2]=v.z; lds[r][q*16+u4*4+3]=v.w;
  }
  __syncthreads();
  #pragma unroll
  for (int u4=0; u4<4; ++u4){
    f32x4 o;
    o.x = lds[q*16+u4*4+0][r]; o.y = lds[q*16+u4*4+1][r];
    o.z = lds[q*16+u4*4+2][r]; o.w = lds[q*16+u4*4+3][r];
    *(f32x4*)&XT[((size_t)g*256 + n0 + r)*512 + c0 + q*16 + u4*4] = o;
  }
}

// s_at [g][c][n] u8 -> sT [g][n][c] u8
__global__ __launch_bounds__(256) void u8_trans(const u8* __restrict__ S, u8* __restrict__ ST){
  __shared__ u8 lds[64][65];
  const int g = blockIdx.z, c0 = blockIdx.y<<6, n0 = blockIdx.x<<6;
  const int t = threadIdx.x, r = t>>2, q = t&3;
  int4v v = *(const int4v*)&S[((size_t)g*512 + c0 + r)*256 + n0 + q*16];
  const u8* pb = (const u8*)&v;
  #pragma unroll
  for (int u=0; u<16; ++u) lds[r][q*16+u] = pb[u];
  __syncthreads();
  u8 ob[16];
  #pragma unroll
  for (int u=0; u<16; ++u) ob[u] = lds[q*16+u][r];
  *(int4v*)&ST[((size_t)g*256 + n0 + r)*512 + c0 + q*16] = *(int4v*)ob;
}

// colsum over (g,n) per c, fp64
template<typename T>
__global__ __launch_bounds__(256) void colsum_k(const T* __restrict__ X, double* __restrict__ cs){
  __shared__ double sh[256];
  const int c = blockIdx.x;
  double s = 0.0;
  for (int g=0; g<NG; ++g) s += (double)X[((size_t)g*512+c)*256 + threadIdx.x];
  double t = blk_reduce(s, sh);
  if (threadIdx.x==0) cs[c] = t;
}

// per-(g,n) column 2-norm over c, fp64
template<typename T>
__global__ __launch_bounds__(256) void norm_k(const T* __restrict__ X, double* __restrict__ nrm){
  const int g = blockIdx.x, n = threadIdx.x;
  double s = 0.0;
  for (int c=0; c<512; ++c){ double v = (double)X[((size_t)g*512+c)*256 + n]; s += v*v; }
  nrm[g*256+n] = sqrt(s);
}

// ---------------------------------------------------------------------------
// G = sum_g X_g X_g^T fp64 (512x512), lower-tri 128-tile pairs, fp64 atomics.
// ---------------------------------------------------------------------------
__global__ __launch_bounds__(256) void gramx(const float* __restrict__ X, double* __restrict__ G){
  const int ti_tab[10] = {0,1,1,2,2,2,3,3,3,3};
  const int tj_tab[10] = {0,0,1,0,1,2,0,1,2,3};
  const int p = blockIdx.x, g = blockIdx.y;
  const int ci0 = ti_tab[p]<<7, cj0 = tj_tab[p]<<7;
  const bool offd = (ci0 != cj0);
  __shared__ float A[32][132];
  __shared__ float Bm[32][132];
  double acc[8][8];
  #pragma unroll
  for (int i=0;i<8;++i)
    #pragma unroll
    for (int j=0;j<8;++j) acc[i][j]=0.0;
  const int tid = threadIdx.x, tx = tid&15, ty = tid>>4;

  for (int nc=0; nc<8; ++nc){
    const int n0 = nc*32;
    __syncthreads();
    #pragma unroll
    for (int s2=0; s2<2; ++s2){
      int S = tid*2+s2, r = S>>2, q = S&3;
      f32x4 a0 = *(const f32x4*)&X[((size_t)g*512 + ci0 + r)*256 + n0 + q*8];
      f32x4 a1 = *(const f32x4*)&X[((size_t)g*512 + ci0 + r)*256 + n0 + q*8 + 4];
      A[q*8+0][r]=a0.x; A[q*8+1][r]=a0.y; A[q*8+2][r]=a0.z; A[q*8+3][r]=a0.w;
      A[q*8+4][r]=a1.x; A[q*8+5][r]=a1.y; A[q*8+6][r]=a1.z; A[q*8+7][r]=a1.w;
      f32x4 b0 = *(const f32x4*)&X[((size_t)g*512 + cj0 + r)*256 + n0 + q*8];
      f32x4 b1 = *(const f32x4*)&X[((size_t)g*512 + cj0 + r)*256 + n0 + q*8 + 4];
      Bm[q*8+0][r]=b0.x; Bm[q*8+1][r]=b0.y; Bm[q*8+2][r]=b0.z; Bm[q*8+3][r]=b0.w;
      Bm[q*8+4][r]=b1.x; Bm[q*8+5][r]=b1.y; Bm[q*8+6][r]=b1.z; Bm[q*8+7][r]=b1.w;
    }
    __syncthreads();
    #pragma unroll
    for (int k=0;k<32;++k){
      f32x4 a0 = *(const f32x4*)&A[k][ty*8];
      f32x4 a1 = *(const f32x4*)&A[k][ty*8+4];
      f32x4 b0 = *(const f32x4*)&Bm[k][tx*8];
      f32x4 b1 = *(const f32x4*)&Bm[k][tx*8+4];
      double a[8], b[8];
      a[0]=a0.x;a[1]=a0.y;a[2]=a0.z;a[3]=a0.w;a[4]=a1.x;a[5]=a1.y;a[6]=a1.z;a[7]=a1.w;
      b[0]=b0.x;b[1]=b0.y;b[2]=b0.z;b[3]=b0.w;b[4]=b1.x;b[5]=b1.y;b[6]=b1.z;b[7]=b1.w;
      #pragma unroll
      for (int i=0;i<8;++i)
        #pragma unroll
        for (int j=0;j<8;++j) acc[i][j] = fma(a[i], b[j], acc[i][j]);
    }
  }
  #pragma unroll
  for (int i=0;i<8;++i){
    int ci = ci0 + ty*8 + i;
    #pragma unroll
    for (int j=0;j<8;++j){
      int cj = cj0 + tx*8 + j;
      atomicAdd(&G[(size_t)ci*512 + cj], acc[i][j]);
      if (offd) atomicAdd(&G[(size_t)cj*512 + ci], acc[i][j]);
    }
  }
}

// ---------------------------------------------------------------------------
// M[o][c'] = sum_k W[o][k] G[k][c']  fp64, k-sliced over blockIdx.z + atomics
// ---------------------------------------------------------------------------
template<typename GT>
__global__ __launch_bounds__(256) void mgemm(const float* __restrict__ W, const GT* __restrict__ G,
                                             double* __restrict__ M){
  const int o0 = blockIdx.y<<6, c0 = blockIdx.x<<6;
  const int k0base = blockIdx.z*128;
  __shared__ float  wT[32][68];
  __shared__ double gS[32][66];
  double acc[4][4];
  #pragma unroll
  for (int i=0;i<4;++i)
    #pragma unroll
    for (int j=0;j<4;++j) acc[i][j]=0.0;
  const int tid = threadIdx.x, tx = tid&15, ty = tid>>4;

  for (int kc=0; kc<4; ++kc){
    const int k0 = k0base + kc*32;
    __syncthreads();
    { int r = tid>>2, q = tid&3;  // W: 64o x 32k -> wT[k][o]
      f32x4 w0 = *(const f32x4*)&W[(size_t)(o0+r)*512 + k0 + q*8];
      f32x4 w1 = *(const f32x4*)&W[(size_t)(o0+r)*512 + k0 + q*8 + 4];
      wT[q*8+0][r]=w0.x; wT[q*8+1][r]=w0.y; wT[q*8+2][r]=w0.z; wT[q*8+3][r]=w0.w;
      wT[q*8+4][r]=w1.x; wT[q*8+5][r]=w1.y; wT[q*8+6][r]=w1.z; wT[q*8+7][r]=w1.w;
      int k = tid>>3, h = tid&7;  // G rows: 32k x 64c
      #pragma unroll
      for (int u=0;u<8;++u) gS[k][h*8+u] = (double)G[(size_t)(k0+k)*512 + c0 + h*8 + u];
    }
    __syncthreads();
    #pragma unroll
    for (int k=0;k<32;++k){
      f32x4 aw = *(const f32x4*)&wT[k][ty*4];
      double a[4] = {(double)aw.x,(double)aw.y,(double)aw.z,(double)aw.w};
      double b[4];
      #pragma unroll
      for (int j=0;j<4;++j) b[j] = gS[k][tx*4+j];
      #pragma unroll
      for (int i=0;i<4;++i)
        #pragma unroll
        for (int j=0;j<4;++j) acc[i][j] = fma(a[i], b[j], acc[i][j]);
    }
  }
  #pragma unroll
  for (int i=0;i<4;++i)
    #pragma unroll
    for (int j=0;j<4;++j)
      atomicAdd(&M[(size_t)(o0+ty*4+i)*512 + c0+tx*4+j], acc[i][j]);
}

// stats: scale[o] = gamma*rsqrt(var+eps), shift[o] = beta - mean*scale
// from S1 = w_o . colsum, S2 = w_o^T G w_o (= diag(W M))
__global__ __launch_bounds__(256) void finalize_stats(const float* __restrict__ W, const double* __restrict__ M,
                                                      const double* __restrict__ cs,
                                                      const float* __restrict__ gamma, const float* __restrict__ beta,
                                                      double* __restrict__ stats){
  __shared__ double sh[256];
  const int o = blockIdx.x;
  double s1=0.0, s2=0.0;
  for (int c = threadIdx.x; c < 512; c += 256){
    double w = (double)W[(size_t)o*512+c];
    s1 += w*cs[c]; s2 += w*M[(size_t)o*512+c];
  }
  double t1 = blk_reduce(s1, sh);
  double t2 = blk_reduce(s2, sh);
  if (threadIdx.x==0){
    double mean = t1*(1.0/16384.0);
    double var  = t2*(1.0/16384.0) - mean*mean;
    double sc = (double)gamma[o] / sqrt(var + 1e-5);
    stats[o] = sc; stats[512+o] = (double)beta[o] - mean*sc;
  }
}

// ---------------------------------------------------------------------------
// Fast bf16-MFMA GEMM. MODE 0: A=Whi/Wlo, B=XT32 f32 (split in staging, 3 prod)
//                      MODE 1: A=Whi/Wlo, B=sT u8 spikes (exact, 2 prod)
// Tile 128o x 128n, 4 waves (64x64 each), k-chunk 32.
// A/B k-pairing is convention-cancelling; m/n = lane&15; D: col=lane&15,
// row=4*(lane>>4)+reg (guide-verified). LDS 16B-slot swizzle qq = q^(r&3).
// ---------------------------------------------------------------------------
template<int MODE>
__global__ __launch_bounds__(256) void fgemm(const ushort* __restrict__ Ahi, const ushort* __restrict__ Alo,
                                             const void* __restrict__ Bsrc, float* __restrict__ Y){
  const int g = blockIdx.z, o0 = blockIdx.y<<7, n0 = blockIdx.x<<7;
  const int tid = threadIdx.x, lane = tid&63, wv = tid>>6;
  const int wo = (wv>>1)<<6, wn2 = (wv&1)<<6;
  const int l15 = lane&15, l4 = lane>>4, ss = l4 ^ (lane&3);
  __shared__ __align__(16) ushort L[4][128][32];
  f32x4 acc[4][4];
  #pragma unroll
  for (int i=0;i<4;++i)
    #pragma unroll
    for (int j=0;j<4;++j) acc[i][j] = f32x4{0.f,0.f,0.f,0.f};

  for (int c0=0; c0<512; c0+=32){
    __syncthreads();
    #pragma unroll
    for (int s2=0; s2<2; ++s2){
      int S = tid*2+s2, r = S>>2, q = S&3, qq = q ^ (r&3);
      *(int4v*)&L[0][r][qq*8] = *(const int4v*)&Ahi[(size_t)(o0+r)*512 + c0 + q*8];
      *(int4v*)&L[1][r][qq*8] = *(const int4v*)&Alo[(size_t)(o0+r)*512 + c0 + q*8];
      if (MODE==0){
        const float* B = (const float*)Bsrc;
        f32x4 x0 = *(const f32x4*)&B[((size_t)g*256 + n0 + r)*512 + c0 + q*8];
        f32x4 x1 = *(const f32x4*)&B[((size_t)g*256 + n0 + r)*512 + c0 + q*8 + 4];
        union { ushort us[8]; int4v v; } hiU, loU;
        float xv[8] = {x0.x,x0.y,x0.z,x0.w,x1.x,x1.y,x1.z,x1.w};
        #pragma unroll
        for (int u=0;u<8;++u){ ushort h = f2bf(xv[u]); hiU.us[u]=h; loU.us[u]=f2bf(xv[u]-bf2f(h)); }
        *(int4v*)&L[2][r][qq*8] = hiU.v;
        *(int4v*)&L[3][r][qq*8] = loU.v;
      } else {
        const u8* B = (const u8*)Bsrc;
        uint2 raw = *(const uint2*)&B[((size_t)g*256 + n0 + r)*512 + c0 + q*8];
        union { ushort us[8]; int4v v; } hiU;
        #pragma unroll
        for (int u=0;u<4;++u) hiU.us[u]   = ((raw.x>>(8*u))&255u) ? 0x3F80 : 0;
        #pragma unroll
        for (int u=0;u<4;++u) hiU.us[4+u] = ((raw.y>>(8*u))&255u) ? 0x3F80 : 0;
        *(int4v*)&L[2][r][qq*8] = hiU.v;
      }
    }
    __syncthreads();
    bf16x8 ah[4], al[4], bh[4], bl[4];
    #pragma unroll
    for (int f=0; f<4; ++f){
      int ra = wo + f*16 + l15;
      ah[f] = *(const bf16x8*)&L[0][ra][ss*8];
      al[f] = *(const bf16x8*)&L[1][ra][ss*8];
      int rb = wn2 + f*16 + l15;
      bh[f] = *(const bf16x8*)&L[2][rb][ss*8];
      if (MODE==0) bl[f] = *(const bf16x8*)&L[3][rb][ss*8];
    }
    #pragma unroll
    for (int of=0; of<4; ++of)
      #pragma unroll
      for (int nf=0; nf<4; ++nf){
        acc[of][nf] = __builtin_amdgcn_mfma_f32_16x16x32_bf16(ah[of], bh[nf], acc[of][nf], 0,0,0);
        acc[of][nf] = __builtin_amdgcn_mfma_f32_16x16x32_bf16(al[of], bh[nf], acc[of][nf], 0,0,0);
        if (MODE==0)
          acc[of][nf] = __builtin_amdgcn_mfma_f32_16x16x32_bf16(ah[of], bl[nf], acc[of][nf], 0,0,0);
      }
  }
  #pragma unroll
  for (int of=0; of<4; ++of)
    #pragma unroll
    for (int nf=0; nf<4; ++nf){
      #pragma unroll
      for (int r=0;r<4;++r){
        int o = o0 + wo + of*16 + l4*4 + r;
        int n = n0 + wn2 + nf*16 + l15;
        Y[((size_t)g*512 + o)*256 + n] = acc[of][nf][r];
      }
    }
}

// ---------------------------------------------------------------------------
// Spike Gram via MFMA (exact integer counts in fp32): Gs[c][c'] += sum s s'
// ---------------------------------------------------------------------------
__global__ __launch_bounds__(256) void sgram(const u8* __restrict__ S, float* __restrict__ Gs){
  const int ci0 = blockIdx.x<<7, cj0 = blockIdx.y<<7, slice = blockIdx.z; // 16 slices x 4 g
  const int tid = threadIdx.x, lane = tid&63, wv = tid>>6;
  const int wo = (wv>>1)<<6, wn2 = (wv&1)<<6;
  const int l15 = lane&15, l4 = lane>>4, ss = l4 ^ (lane&3);
  __shared__ __align__(16) ushort L[2][128][32];
  f32x4 acc[4][4];
  #pragma unroll
  for (int i=0;i<4;++i)
    #pragma unroll
    for (int j=0;j<4;++j) acc[i][j] = f32x4{0.f,0.f,0.f,0.f};

  for (int gg=0; gg<4; ++gg){
    const int g = slice*4+gg;
    for (int nc=0; nc<8; ++nc){
      const int n0 = nc*32;
      __syncthreads();
      #pragma unroll
      for (int s2=0; s2<2; ++s2){
        int Sl = tid*2+s2, r = Sl>>2, q = Sl&3, qq = q ^ (r&3);
        uint2 ra = *(const uint2*)&S[((size_t)g*512 + ci0 + r)*256 + n0 + q*8];
        uint2 rb = *(const uint2*)&S[((size_t)g*512 + cj0 + r)*256 + n0 + q*8];
        union { ushort us[8]; int4v v; } A, Bv;
        #pragma unroll
        for (int u=0;u<4;++u){ A.us[u]   = ((ra.x>>(8*u))&255u)?0x3F80:0; Bv.us[u]   = ((rb.x>>(8*u))&255u)?0x3F80:0; }
        #pragma unroll
        for (int u=0;u<4;++u){ A.us[4+u] = ((ra.y>>(8*u))&255u)?0x3F80:0; Bv.us[4+u] = ((rb.y>>(8*u))&255u)?0x3F80:0; }
        *(int4v*)&L[0][r][qq*8] = A.v;
        *(int4v*)&L[1][r][qq*8] = Bv.v;
      }
      __syncthreads();
      bf16x8 af[4], bfv[4];
      #pragma unroll
      for (int f=0; f<4; ++f){
        int ra = wo + f*16 + l15;  af[f]  = *(const bf16x8*)&L[0][ra][ss*8];
        int rb = wn2 + f*16 + l15; bfv[f] = *(const bf16x8*)&L[1][rb][ss*8];
      }
      #pragma unroll
      for (int of=0; of<4; ++of)
        #pragma unroll
        for (int nf=0; nf<4; ++nf)
          acc[of][nf] = __builtin_amdgcn_mfma_f32_16x16x32_bf16(af[of], bfv[nf], acc[of][nf], 0,0,0);
    }
  }
  #pragma unroll
  for (int of=0; of<4; ++of)
    #pragma unroll
    for (int nf=0; nf<4; ++nf)
      #pragma unroll
      for (int r=0;r<4;++r){
        int ci = ci0 + wo + of*16 + l4*4 + r;
        int cj = cj0 + wn2 + nf*16 + l15;
        atomicAdd(&Gs[(size_t)ci*512 + cj], acc[of][nf][r]);
      }
}

// ---------------------------------------------------------------------------
// BN-affine (fp64 stats) + LIF (theta=1) + spike write + near-margin flagging.
// ---------------------------------------------------------------------------
template<int OUTF>
__global__ __launch_bounds__(256) void bn_lif_flag(const float* __restrict__ Y, const double* __restrict__ stats,
                                                   const double* __restrict__ wn, const double* __restrict__ xn,
                                                   double K, void* __restrict__ sout,
                                                   uint* __restrict__ list, int* __restrict__ cnt){
  const int idx = blockIdx.x*256 + threadIdx.x;
  const int n = idx & 255, o = (idx>>8) & 511, b = idx>>17;
  const double scale = stats[o], shift = stats[512+o];
  const double kw = K * fabs(scale) * wn[o];
  double v = 0.0, minm = 1e300, bmax = 0.0;
  #pragma unroll
  for (int t=0;t<4;++t){
    const int g = t*16+b;
    const size_t ii = ((size_t)g*512+o)*256 + n;
    double y = (double)Y[ii];
    double Bnd = kw * xn[g*256+n]; bmax = fmax(bmax, Bnd);
    double z = y*scale + shift;
    v = v + (z - v)*0.5;
    double m = fabs(v - 1.0) - 2.0*bmax;
    minm = fmin(minm, m);
    bool sp = (v - 1.0) >= 0.0;
    if (OUTF) ((float*)sout)[ii] = sp ? 1.0f : 0.0f;
    else      ((u8*)sout)[ii]    = sp ? 1 : 0;
    if (sp) v = 0.0;
  }
  if (minm < 0.0){
    int pos = atomicAdd(cnt, 1);
    if (pos < CAP) list[pos] = ((uint)b<<17)|((uint)o<<8)|(uint)n;
  }
}

// fp64 exact recompute of flagged cells. Xn layout [g][n][c]: f32 (OUTF=0) / u8 (OUTF=1).
template<int OUTF>
__global__ __launch_bounds__(256) void recompute(const uint* __restrict__ list, const int* __restrict__ cnt,
                                                 const float* __restrict__ W, const void* __restrict__ Xn,
                                                 const double* __restrict__ stats, void* __restrict__ out){
  const int lane = threadIdx.x & 63;
  const int wv = blockIdx.x*4 + (threadIdx.x>>6);
  int ne = *cnt; if (ne > CAP) ne = CAP;
  for (int e = wv; e < ne; e += gridDim.x*4){
    const uint code = list[e];
    const int b = code>>17, o = (code>>8)&511, n = code&255;
    if (b > 15) continue;                       // defensive: never follow garbage
    const double scale = stats[o], shift = stats[512+o];
    double v = 0.0;
    for (int t=0;t<4;++t){
      const int g = t*16+b;
      double y = 0.0;
      #pragma unroll
      for (int i=0;i<8;++i){
        int c = lane + 64*i;
        double w = (double)W[(size_t)o*512 + c];
        double xv;
        if (OUTF) xv = (double)((const u8*)Xn)[((size_t)g*256+n)*512 + c];
        else      xv = (double)((const float*)Xn)[((size_t)g*256+n)*512 + c];
        y = fma(w, xv, y);
      }
      #pragma unroll
      for (int off=32; off>0; off>>=1) y += __shfl_xor(y, off);
      double z = y*scale + shift;
      v = v + (z - v)*0.5;
      bool sp = (v - 1.0) >= 0.0;
      if (lane==0){
        const size_t ii = ((size_t)g*512+o)*256 + n;
        if (OUTF) ((float*)out)[ii] = sp ? 1.0f : 0.0f;
        else      ((u8*)out)[ii]    = sp ? 1 : 0;
      }
      if (sp) v = 0.0;
    }
  }
}

// ---------------------------------------------------------------------------
// LIF (fp64) for the attention values, theta=0.5, exact (dyadic inputs).
// ---------------------------------------------------------------------------
__global__ __launch_bounds__(256) void lif_kernel(const float* __restrict__ Y, double thresh,
                                                  u8* __restrict__ s_u8){
  const size_t idx = (size_t)blockIdx.x * 256 + threadIdx.x;
  double v = 0.0;
  #pragma unroll
  for (int t = 0; t < 4; ++t){
    double z = (double)Y[(size_t)t * BCN + idx];
    v = v + (z - v) * 0.5;
    bool sp = (v - thresh) >= 0.0;
    s_u8[(size_t)t * BCN + idx] = sp ? 1 : 0;
    if (sp) v = 0.0;
  }
}

// ---------------------------------------------------------------------------
// kv[d][e] = sum_n k v  (integer, exact)
// ---------------------------------------------------------------------------
__global__ __launch_bounds__(256) void attn_kv(const u8* __restrict__ sk, const u8* __restrict__ sv,
                                               float* __restrict__ kv){
  const int blk = blockIdx.x;
  const int tid = threadIdx.x;
  const size_t base = ((size_t)(blk >> 3) * 512 + (size_t)(blk & 7) * 64) * 256;
  __shared__ u8 kS[64][256];
  __shared__ u8 vS[64][256];
  const uint32_t* K32 = (const uint32_t*)(sk + base);
  const uint32_t* V32 = (const uint32_t*)(sv + base);
  uint32_t* kS32 = (uint32_t*)&kS[0][0];
  uint32_t* vS32 = (uint32_t*)&vS[0][0];
  #pragma unroll
  for (int i = 0; i < 16; ++i){ kS32[i*256+tid] = K32[i*256+tid]; vS32[i*256+tid] = V32[i*256+tid]; }
  __syncthreads();
  const int d0 = (tid >> 4) << 2, e0 = (tid & 15) << 2;
  int acc[4][4] = {};
  for (int n = 0; n < 256; ++n){
    int k_[4], v_[4];
    #pragma unroll
    for (int i = 0; i < 4; ++i) k_[i] = kS[d0+i][n];
    #pragma unroll
    for (int j = 0; j < 4; ++j) v_[j] = vS[e0+j][n];
    #pragma unroll
    for (int i = 0; i < 4; ++i)
      #pragma unroll
      for (int j = 0; j < 4; ++j) acc[i][j] += k_[i]*v_[j];
  }
  float* KV = kv + (size_t)blk * 4096;
  #pragma unroll
  for (int i = 0; i < 4; ++i)
    #pragma unroll
    for (int j = 0; j < 4; ++j) KV[(d0+i)*64 + e0+j] = (float)acc[i][j];
}

__global__ __launch_bounds__(256) void attn_qkv(const u8* __restrict__ sq, const float* __restrict__ kv,
                                                float* __restrict__ attn){
  const int blk = blockIdx.x;
  const int tid = threadIdx.x;
  const size_t base = ((size_t)(blk >> 3) * 512 + (size_t)(blk & 7) * 64) * 256;
  __shared__ u8 qS[64][256];
  __shared__ float kvS[64][64];
  const uint32_t* Q32 = (const uint32_t*)(sq + base);
  uint32_t* qS32 = (uint32_t*)&qS[0][0];
  const float* KV = kv + (size_t)blk * 4096;
  #pragma unroll
  for (int i = 0; i < 16; ++i){
    qS32[i*256+tid] = Q32[i*256+tid];
    (&kvS[0][0])[i*256+tid] = KV[i*256+tid];
  }
  __syncthreads();
  const int n = tid;
  float acc[64];
  #pragma unroll
  for (int e = 0; e < 64; ++e) acc[e] = 0.0f;
  for (int d = 0; d < 64; ++d){
    float qf = (float)qS[d][n];
    #pragma unroll
    for (int e = 0; e < 64; ++e) acc[e] = fmaf(qf, kvS[d][e], acc[e]);
  }
  float* A = attn + base;
  #pragma unroll
  for (int e = 0; e < 64; ++e) A[(size_t)e*256 + n] = acc[e]*0.125f;
}

// ---------------------------------------------------------------------------
extern "C" void kernel_launch(void* const* d_in, const int* in_sizes, int n_in,
                              void* d_out, int out_size, void* d_ws, size_t ws_size,
                              hipStream_t stream){
  const float* x       = (const float*)d_in[0];
  const float* Wb[4]   = {(const float*)d_in[1], (const float*)d_in[4], (const float*)d_in[7], (const float*)d_in[10]};
  const float* Gm[4]   = {(const float*)d_in[2], (const float*)d_in[5], (const float*)d_in[8], (const float*)d_in[12]};
  const float* Bt[4]   = {(const float*)d_in[3], (const float*)d_in[6], (const float*)d_in[9], (const float*)d_in[13]};
  // d_in[11] = proj_b: cancels exactly inside training-mode BN -> unused.

  char* p = (char*)d_ws;
  float* yA   = (float*)p;            p += 33554432;
  u8* s_q     = (u8*)p;               p += 8388608;
  u8* s_k     = (u8*)p;               p += 8388608;
  u8* s_v     = (u8*)p;               p += 8388608;
  u8* s_at    = (u8*)p;               p += 8388608;
  float* XT32 = (float*)p;
  u8* sT      = (u8*)p;               p += 33554432;   // sT aliases XT32 (XT32 dead before proj)
  ushort* Whl = (ushort*)p;           p += 4194304;    // [4 mats][hi 262144 | lo 262144] ushorts
  float* kvb  = (float*)p;            p += 8388608;
  double* G   = (double*)p;           p += 2097152;
  float* Gs   = (float*)p;            p += 1048576;
  double* M   = (double*)p;           p += 2097152;
  double* colsumX = (double*)p;       p += 4096;
  double* colsumS = (double*)p;       p += 4096;
  double* xnorm   = (double*)p;       p += 131072;
  double* snorm   = (double*)p;       p += 131072;
  double* wn      = (double*)p;       p += 16384;      // [4][512]
  double* stats   = (double*)p;       p += 32768;      // [4][1024]
  int*    cnt     = (int*)p;          p += 256;
  uint*   lists   = (uint*)p;         p += 4*CAP*4;    // [4][CAP] uints
  const size_t NEED = (size_t)(p - (char*)d_ws);

  if (ws_size < NEED){
    guard_fill<<<(out_size+255)/256, 256, 0, stream>>>((float*)d_out, out_size);
    return;
  }

  const double K0 = 1.2e-4;   // qkv fast-path bound const (2x over 6e-5 worst-case)
  const double K1 = 6.0e-5;   // proj (B exact 0/1)

  hipMemsetAsync(G,   0, 2097152, stream);
  hipMemsetAsync(Gs,  0, 1048576, stream);
  hipMemsetAsync(cnt, 0, 256,     stream);

  for (int i=0;i<4;++i){
    w_split<<<1024, 256, 0, stream>>>(Wb[i], Whl + (size_t)i*524288, Whl + (size_t)i*524288 + 262144);
    wnorm_k<<<512, 256, 0, stream>>>(Wb[i], wn + i*512);
  }
  xtrans32<<<dim3(4,8,64), 256, 0, stream>>>(x, XT32);
  colsum_k<float><<<512, 256, 0, stream>>>(x, colsumX);
  norm_k<float><<<64, 256, 0, stream>>>(x, xnorm);
  gramx<<<dim3(10,64), 256, 0, stream>>>(x, G);

  u8* sOut[3] = {s_q, s_k, s_v};
  for (int i=0;i<3;++i){
    hipMemsetAsync(M, 0, 2097152, stream);
    mgemm<double><<<dim3(8,8,4), 256, 0, stream>>>(Wb[i], G, M);
    finalize_stats<<<512, 256, 0, stream>>>(Wb[i], M, colsumX, Gm[i], Bt[i], stats + i*1024);
    fgemm<0><<<dim3(2,4,64), 256, 0, stream>>>(Whl + (size_t)i*524288, Whl + (size_t)i*524288 + 262144, XT32, yA);
    bn_lif_flag<0><<<8192, 256, 0, stream>>>(yA, stats + i*1024, wn + i*512, xnorm, K0,
                                             sOut[i], lists + (size_t)i*CAP, cnt + i);
    recompute<0><<<512, 256, 0, stream>>>(lists + (size_t)i*CAP, cnt + i, Wb[i], XT32, stats + i*1024, sOut[i]);
  }

  attn_kv<<<512, 256, 0, stream>>>(s_k, s_v, kvb);
  attn_qkv<<<512, 256, 0, stream>>>(s_q, kvb, yA);
  lif_kernel<<<8192, 256, 0, stream>>>(yA, 0.5, s_at);

  u8_trans<<<dim3(4,8,64), 256, 0, stream>>>(s_at, sT);
  colsum_k<u8><<<512, 256, 0, stream>>>(s_at, colsumS);
  norm_k<u8><<<64, 256, 0, stream>>>(s_at, snorm);
  sgram<<<dim3(4,4,16), 256, 0, stream>>>(s_at, Gs);

  hipMemsetAsync(M, 0, 2097152, stream);
  mgemm<float><<<dim3(8,8,4), 256, 0, stream>>>(Wb[3], Gs, M);
  finalize_stats<<<512, 256, 0, stream>>>(Wb[3], M, colsumS, Gm[3], Bt[3], stats + 3*1024);
  fgemm<1><<<dim3(2,4,64), 256, 0, stream>>>(Whl + (size_t)3*524288, Whl + (size_t)3*524288 + 262144, sT, yA);
  bn_lif_flag<1><<<8192, 256, 0, stream>>>(yA, stats + 3*1024, wn + 3*512, snorm, K1,
                                           d_out, lists + (size_t)3*CAP, cnt + 3);
  recompute<1><<<512, 256, 0, stream>>>(lists + (size_t)3*CAP, cnt + 3, Wb[3], sT, stats + 3*1024, d_out);
}

// Round 7
// 1048.960 us; speedup vs baseline: 2.0180x; 2.0180x over previous
//
#include <hip/hip_runtime.h>
#include <hip/hip_bf16.h>
#include <stdint.h>

// Dims: T=4, B=16, C=512, N=256 (16x16). heads=8, d=64. groups g = t*16+b (64).
#define BCN  (16*512*256)
#define CN   (512*256)
#define NG   64
#define CAP  65536

typedef __attribute__((ext_vector_type(8))) short bf16x8;
typedef __attribute__((ext_vector_type(4))) float f32x4;
typedef __attribute__((ext_vector_type(4))) int   int4v;
typedef unsigned char u8;

__device__ inline ushort f2bf(float x){ union{ __hip_bfloat16 b; ushort u; } z; z.b = __float2bfloat16(x); return z.u; }
__device__ inline float  bf2f(ushort u){ union{ uint i; float f; } z; z.i = (uint)u<<16; return z.f; }

__device__ inline double blk_reduce(double v, double* sh){
  int tid = threadIdx.x; sh[tid] = v; __syncthreads();
  for (int off=128; off>0; off>>=1){ if (tid<off) sh[tid]+=sh[tid+off]; __syncthreads(); }
  double r = sh[0]; __syncthreads(); return r;
}

// ---------------------------------------------------------------------------
__global__ __launch_bounds__(256) void guard_fill(float* out, int n){
  int i = blockIdx.x*256+threadIdx.x; if (i<n) out[i] = -1.0f;
}

// W (f32 [o][c]) -> Whi/Wlo bf16 [o][c]
__global__ __launch_bounds__(256) void w_split(const float* __restrict__ W,
                                               ushort* __restrict__ Whi, ushort* __restrict__ Wlo){
  int i = blockIdx.x*256+threadIdx.x; if (i >= 512*512) return;
  float x = W[i]; ushort h = f2bf(x);
  Whi[i] = h; Wlo[i] = f2bf(x - bf2f(h));
}

// ||W[o,:]||_2 fp64
__global__ __launch_bounds__(256) void wnorm_k(const float* __restrict__ W, double* __restrict__ wn){
  __shared__ double sh[256];
  int o = blockIdx.x;
  double s = 0.0;
  for (int c = threadIdx.x; c < 512; c += 256){ double w = (double)W[o*512+c]; s += w*w; }
  double t = blk_reduce(s, sh);
  if (threadIdx.x==0) wn[o] = sqrt(t);
}

// X [g][c][n] f32 -> XT32 [g][n][c] f32   (64x64 tiles)
__global__ __launch_bounds__(256) void xtrans32(const float* __restrict__ X, float* __restrict__ XT){
  __shared__ float lds[64][65];
  const int g = blockIdx.z, c0 = blockIdx.y<<6, n0 = blockIdx.x<<6;
  const int t = threadIdx.x, r = t>>2, q = t&3;
  #pragma unroll
  for (int u4=0; u4<4; ++u4){
    f32x4 v = *(const f32x4*)&X[((size_t)g*512 + c0 + r)*256 + n0 + q*16 + u4*4];
    lds[r][q*16+u4*4+0]=v.x; lds[r][q*16+u4*4+1]=v.y; lds[r][q*16+u4*4+2]=v.z; lds[r][q*16+u4*4+3]=v.w;
  }
  __syncthreads();
  #pragma unroll
  for (int u4=0; u4<4; ++u4){
    f32x4 o;
    o.x = lds[q*16+u4*4+0][r]; o.y = lds[q*16+u4*4+1][r];
    o.z = lds[q*16+u4*4+2][r]; o.w = lds[q*16+u4*4+3][r];
    *(f32x4*)&XT[((size_t)g*256 + n0 + r)*512 + c0 + q*16 + u4*4] = o;
  }
}

// s_at [g][c][n] u8 -> sT [g][n][c] u8
__global__ __launch_bounds__(256) void u8_trans(const u8* __restrict__ S, u8* __restrict__ ST){
  __shared__ u8 lds[64][65];
  const int g = blockIdx.z, c0 = blockIdx.y<<6, n0 = blockIdx.x<<6;
  const int t = threadIdx.x, r = t>>2, q = t&3;
  int4v v = *(const int4v*)&S[((size_t)g*512 + c0 + r)*256 + n0 + q*16];
  const u8* pb = (const u8*)&v;
  #pragma unroll
  for (int u=0; u<16; ++u) lds[r][q*16+u] = pb[u];
  __syncthreads();
  u8 ob[16];
  #pragma unroll
  for (int u=0; u<16; ++u) ob[u] = lds[q*16+u][r];
  *(int4v*)&ST[((size_t)g*256 + n0 + r)*512 + c0 + q*16] = *(int4v*)ob;
}

// colsum over (g,n) per c, fp64
template<typename T>
__global__ __launch_bounds__(256) void colsum_k(const T* __restrict__ X, double* __restrict__ cs){
  __shared__ double sh[256];
  const int c = blockIdx.x;
  double s = 0.0;
  for (int g=0; g<NG; ++g) s += (double)X[((size_t)g*512+c)*256 + threadIdx.x];
  double t = blk_reduce(s, sh);
  if (threadIdx.x==0) cs[c] = t;
}

// per-(g,n) column 2-norm over c, fp64
template<typename T>
__global__ __launch_bounds__(256) void norm_k(const T* __restrict__ X, double* __restrict__ nrm){
  const int g = blockIdx.x, n = threadIdx.x;
  double s = 0.0;
  for (int c=0; c<512; ++c){ double v = (double)X[((size_t)g*512+c)*256 + n]; s += v*v; }
  nrm[g*256+n] = sqrt(s);
}

// ---------------------------------------------------------------------------
// gramx2: Gpart[z][ci][cj] = sum_{g in slice z, n} X[g][ci][n] X[g][cj][n], fp64.
// 64x64 tile per block, acc 4x4/thread (32 VGPR — no spill), NON-atomic
// per-slice partials. grid (8,8,16). LDS tiles stored [n][c] for b128 reads.
// ---------------------------------------------------------------------------
__global__ __launch_bounds__(256, 4) void gramx2(const float* __restrict__ X, double* __restrict__ Gpart){
  const int ci0 = blockIdx.x<<6, cj0 = blockIdx.y<<6, z = blockIdx.z;
  const int tid = threadIdx.x, tx = tid&15, ty = tid>>4;
  __shared__ float A[64][68];
  __shared__ float B[64][68];
  double acc[4][4] = {};

  for (int gg=0; gg<4; ++gg){
    const int g = z*4+gg;
    for (int nc=0; nc<4; ++nc){
      const int n0 = nc<<6;
      __syncthreads();
      { const int r = tid>>2, q = tid&3;
        #pragma unroll
        for (int u=0; u<4; ++u){
          f32x4 va = *(const f32x4*)&X[((size_t)g*512 + ci0 + r)*256 + n0 + q*16 + u*4];
          A[q*16+u*4+0][r]=va.x; A[q*16+u*4+1][r]=va.y; A[q*16+u*4+2][r]=va.z; A[q*16+u*4+3][r]=va.w;
          f32x4 vb = *(const f32x4*)&X[((size_t)g*512 + cj0 + r)*256 + n0 + q*16 + u*4];
          B[q*16+u*4+0][r]=vb.x; B[q*16+u*4+1][r]=vb.y; B[q*16+u*4+2][r]=vb.z; B[q*16+u*4+3][r]=vb.w;
        }
      }
      __syncthreads();
      #pragma unroll 8
      for (int n=0; n<64; ++n){
        const f32x4 af = *(const f32x4*)&A[n][ty*4];
        const f32x4 bf = *(const f32x4*)&B[n][tx*4];
        double a[4] = {(double)af.x,(double)af.y,(double)af.z,(double)af.w};
        double b[4] = {(double)bf.x,(double)bf.y,(double)bf.z,(double)bf.w};
        #pragma unroll
        for (int i=0;i<4;++i)
          #pragma unroll
          for (int j=0;j<4;++j) acc[i][j] = fma(a[i], b[j], acc[i][j]);
      }
    }
  }
  double* Gp = Gpart + (size_t)z*262144;
  #pragma unroll
  for (int i=0;i<4;++i)
    #pragma unroll
    for (int j=0;j<4;++j)
      Gp[(size_t)(ci0+ty*4+i)*512 + cj0+tx*4+j] = acc[i][j];
}

__global__ __launch_bounds__(256) void greduce64(const double* __restrict__ Gpart, double* __restrict__ G){
  const int i = blockIdx.x*256 + threadIdx.x;      // 262144
  double s = 0.0;
  #pragma unroll
  for (int z=0; z<16; ++z) s += Gpart[(size_t)z*262144 + i];
  G[i] = s;
}

__global__ __launch_bounds__(256) void greduceS(const float* __restrict__ Gspart, float* __restrict__ Gs){
  const int i = blockIdx.x*256 + threadIdx.x;
  float s = 0.0f;
  #pragma unroll
  for (int z=0; z<16; ++z) s += Gspart[(size_t)z*262144 + i];
  Gs[i] = s;
}

// ---------------------------------------------------------------------------
// M[o][c'] = sum_k W[o][k] G[k][c']  fp64, k-sliced over blockIdx.z + atomics
// ---------------------------------------------------------------------------
template<typename GT>
__global__ __launch_bounds__(256) void mgemm(const float* __restrict__ W, const GT* __restrict__ G,
                                             double* __restrict__ M){
  const int o0 = blockIdx.y<<6, c0 = blockIdx.x<<6;
  const int k0base = blockIdx.z*128;
  __shared__ float  wT[32][68];
  __shared__ double gS[32][66];
  double acc[4][4];
  #pragma unroll
  for (int i=0;i<4;++i)
    #pragma unroll
    for (int j=0;j<4;++j) acc[i][j]=0.0;
  const int tid = threadIdx.x, tx = tid&15, ty = tid>>4;

  for (int kc=0; kc<4; ++kc){
    const int k0 = k0base + kc*32;
    __syncthreads();
    { int r = tid>>2, q = tid&3;  // W: 64o x 32k -> wT[k][o]
      f32x4 w0 = *(const f32x4*)&W[(size_t)(o0+r)*512 + k0 + q*8];
      f32x4 w1 = *(const f32x4*)&W[(size_t)(o0+r)*512 + k0 + q*8 + 4];
      wT[q*8+0][r]=w0.x; wT[q*8+1][r]=w0.y; wT[q*8+2][r]=w0.z; wT[q*8+3][r]=w0.w;
      wT[q*8+4][r]=w1.x; wT[q*8+5][r]=w1.y; wT[q*8+6][r]=w1.z; wT[q*8+7][r]=w1.w;
      int k = tid>>3, h = tid&7;  // G rows: 32k x 64c
      #pragma unroll
      for (int u=0;u<8;++u) gS[k][h*8+u] = (double)G[(size_t)(k0+k)*512 + c0 + h*8 + u];
    }
    __syncthreads();
    #pragma unroll
    for (int k=0;k<32;++k){
      f32x4 aw = *(const f32x4*)&wT[k][ty*4];
      double a[4] = {(double)aw.x,(double)aw.y,(double)aw.z,(double)aw.w};
      double b[4];
      #pragma unroll
      for (int j=0;j<4;++j) b[j] = gS[k][tx*4+j];
      #pragma unroll
      for (int i=0;i<4;++i)
        #pragma unroll
        for (int j=0;j<4;++j) acc[i][j] = fma(a[i], b[j], acc[i][j]);
    }
  }
  #pragma unroll
  for (int i=0;i<4;++i)
    #pragma unroll
    for (int j=0;j<4;++j)
      atomicAdd(&M[(size_t)(o0+ty*4+i)*512 + c0+tx*4+j], acc[i][j]);
}

// stats: scale[o] = gamma*rsqrt(var+eps), shift[o] = beta - mean*scale
__global__ __launch_bounds__(256) void finalize_stats(const float* __restrict__ W, const double* __restrict__ M,
                                                      const double* __restrict__ cs,
                                                      const float* __restrict__ gamma, const float* __restrict__ beta,
                                                      double* __restrict__ stats){
  __shared__ double sh[256];
  const int o = blockIdx.x;
  double s1=0.0, s2=0.0;
  for (int c = threadIdx.x; c < 512; c += 256){
    double w = (double)W[(size_t)o*512+c];
    s1 += w*cs[c]; s2 += w*M[(size_t)o*512+c];
  }
  double t1 = blk_reduce(s1, sh);
  double t2 = blk_reduce(s2, sh);
  if (threadIdx.x==0){
    double mean = t1*(1.0/16384.0);
    double var  = t2*(1.0/16384.0) - mean*mean;
    double sc = (double)gamma[o] / sqrt(var + 1e-5);
    stats[o] = sc; stats[512+o] = (double)beta[o] - mean*sc;
  }
}

// ---------------------------------------------------------------------------
// Fast bf16-MFMA GEMM. MODE 0: A=Whi/Wlo, B=XT32 f32 (split in staging, 3 prod)
//                      MODE 1: A=Whi/Wlo, B=sT u8 spikes (exact, 2 prod)
// ---------------------------------------------------------------------------
template<int MODE>
__global__ __launch_bounds__(256) void fgemm(const ushort* __restrict__ Ahi, const ushort* __restrict__ Alo,
                                             const void* __restrict__ Bsrc, float* __restrict__ Y){
  const int g = blockIdx.z, o0 = blockIdx.y<<7, n0 = blockIdx.x<<7;
  const int tid = threadIdx.x, lane = tid&63, wv = tid>>6;
  const int wo = (wv>>1)<<6, wn2 = (wv&1)<<6;
  const int l15 = lane&15, l4 = lane>>4, ss = l4 ^ (lane&3);
  __shared__ __align__(16) ushort L[4][128][32];
  f32x4 acc[4][4];
  #pragma unroll
  for (int i=0;i<4;++i)
    #pragma unroll
    for (int j=0;j<4;++j) acc[i][j] = f32x4{0.f,0.f,0.f,0.f};

  for (int c0=0; c0<512; c0+=32){
    __syncthreads();
    #pragma unroll
    for (int s2=0; s2<2; ++s2){
      int S = tid*2+s2, r = S>>2, q = S&3, qq = q ^ (r&3);
      *(int4v*)&L[0][r][qq*8] = *(const int4v*)&Ahi[(size_t)(o0+r)*512 + c0 + q*8];
      *(int4v*)&L[1][r][qq*8] = *(const int4v*)&Alo[(size_t)(o0+r)*512 + c0 + q*8];
      if (MODE==0){
        const float* B = (const float*)Bsrc;
        f32x4 x0 = *(const f32x4*)&B[((size_t)g*256 + n0 + r)*512 + c0 + q*8];
        f32x4 x1 = *(const f32x4*)&B[((size_t)g*256 + n0 + r)*512 + c0 + q*8 + 4];
        union { ushort us[8]; int4v v; } hiU, loU;
        float xv[8] = {x0.x,x0.y,x0.z,x0.w,x1.x,x1.y,x1.z,x1.w};
        #pragma unroll
        for (int u=0;u<8;++u){ ushort h = f2bf(xv[u]); hiU.us[u]=h; loU.us[u]=f2bf(xv[u]-bf2f(h)); }
        *(int4v*)&L[2][r][qq*8] = hiU.v;
        *(int4v*)&L[3][r][qq*8] = loU.v;
      } else {
        const u8* B = (const u8*)Bsrc;
        uint2 raw = *(const uint2*)&B[((size_t)g*256 + n0 + r)*512 + c0 + q*8];
        union { ushort us[8]; int4v v; } hiU;
        #pragma unroll
        for (int u=0;u<4;++u) hiU.us[u]   = ((raw.x>>(8*u))&255u) ? 0x3F80 : 0;
        #pragma unroll
        for (int u=0;u<4;++u) hiU.us[4+u] = ((raw.y>>(8*u))&255u) ? 0x3F80 : 0;
        *(int4v*)&L[2][r][qq*8] = hiU.v;
      }
    }
    __syncthreads();
    bf16x8 ah[4], al[4], bh[4], bl[4];
    #pragma unroll
    for (int f=0; f<4; ++f){
      int ra = wo + f*16 + l15;
      ah[f] = *(const bf16x8*)&L[0][ra][ss*8];
      al[f] = *(const bf16x8*)&L[1][ra][ss*8];
      int rb = wn2 + f*16 + l15;
      bh[f] = *(const bf16x8*)&L[2][rb][ss*8];
      if (MODE==0) bl[f] = *(const bf16x8*)&L[3][rb][ss*8];
    }
    #pragma unroll
    for (int of=0; of<4; ++of)
      #pragma unroll
      for (int nf=0; nf<4; ++nf){
        acc[of][nf] = __builtin_amdgcn_mfma_f32_16x16x32_bf16(ah[of], bh[nf], acc[of][nf], 0,0,0);
        acc[of][nf] = __builtin_amdgcn_mfma_f32_16x16x32_bf16(al[of], bh[nf], acc[of][nf], 0,0,0);
        if (MODE==0)
          acc[of][nf] = __builtin_amdgcn_mfma_f32_16x16x32_bf16(ah[of], bl[nf], acc[of][nf], 0,0,0);
      }
  }
  #pragma unroll
  for (int of=0; of<4; ++of)
    #pragma unroll
    for (int nf=0; nf<4; ++nf){
      #pragma unroll
      for (int r=0;r<4;++r){
        int o = o0 + wo + of*16 + l4*4 + r;
        int n = n0 + wn2 + nf*16 + l15;
        Y[((size_t)g*512 + o)*256 + n] = acc[of][nf][r];
      }
    }
}

// ---------------------------------------------------------------------------
// Spike Gram via MFMA (exact integer counts in fp32), NON-atomic per-slice
// partials Gspart[16][512x512].
// ---------------------------------------------------------------------------
__global__ __launch_bounds__(256) void sgram(const u8* __restrict__ S, float* __restrict__ Gspart){
  const int ci0 = blockIdx.x<<7, cj0 = blockIdx.y<<7, slice = blockIdx.z; // 16 slices x 4 g
  const int tid = threadIdx.x, lane = tid&63, wv = tid>>6;
  const int wo = (wv>>1)<<6, wn2 = (wv&1)<<6;
  const int l15 = lane&15, l4 = lane>>4, ss = l4 ^ (lane&3);
  __shared__ __align__(16) ushort L[2][128][32];
  f32x4 acc[4][4];
  #pragma unroll
  for (int i=0;i<4;++i)
    #pragma unroll
    for (int j=0;j<4;++j) acc[i][j] = f32x4{0.f,0.f,0.f,0.f};

  for (int gg=0; gg<4; ++gg){
    const int g = slice*4+gg;
    for (int nc=0; nc<8; ++nc){
      const int n0 = nc*32;
      __syncthreads();
      #pragma unroll
      for (int s2=0; s2<2; ++s2){
        int Sl = tid*2+s2, r = Sl>>2, q = Sl&3, qq = q ^ (r&3);
        uint2 ra = *(const uint2*)&S[((size_t)g*512 + ci0 + r)*256 + n0 + q*8];
        uint2 rb = *(const uint2*)&S[((size_t)g*512 + cj0 + r)*256 + n0 + q*8];
        union { ushort us[8]; int4v v; } A, Bv;
        #pragma unroll
        for (int u=0;u<4;++u){ A.us[u]   = ((ra.x>>(8*u))&255u)?0x3F80:0; Bv.us[u]   = ((rb.x>>(8*u))&255u)?0x3F80:0; }
        #pragma unroll
        for (int u=0;u<4;++u){ A.us[4+u] = ((ra.y>>(8*u))&255u)?0x3F80:0; Bv.us[4+u] = ((rb.y>>(8*u))&255u)?0x3F80:0; }
        *(int4v*)&L[0][r][qq*8] = A.v;
        *(int4v*)&L[1][r][qq*8] = Bv.v;
      }
      __syncthreads();
      bf16x8 af[4], bfv[4];
      #pragma unroll
      for (int f=0; f<4; ++f){
        int ra = wo + f*16 + l15;  af[f]  = *(const bf16x8*)&L[0][ra][ss*8];
        int rb = wn2 + f*16 + l15; bfv[f] = *(const bf16x8*)&L[1][rb][ss*8];
      }
      #pragma unroll
      for (int of=0; of<4; ++of)
        #pragma unroll
        for (int nf=0; nf<4; ++nf)
          acc[of][nf] = __builtin_amdgcn_mfma_f32_16x16x32_bf16(af[of], bfv[nf], acc[of][nf], 0,0,0);
    }
  }
  float* Gp = Gspart + (size_t)slice*262144;
  #pragma unroll
  for (int of=0; of<4; ++of)
    #pragma unroll
    for (int nf=0; nf<4; ++nf)
      #pragma unroll
      for (int r=0;r<4;++r){
        int ci = ci0 + wo + of*16 + l4*4 + r;
        int cj = cj0 + wn2 + nf*16 + l15;
        Gp[(size_t)ci*512 + cj] = acc[of][nf][r];
      }
}

// ---------------------------------------------------------------------------
// BN-affine (fp64 stats) + LIF (theta=1) + spike write + near-margin flagging.
// ---------------------------------------------------------------------------
template<int OUTF>
__global__ __launch_bounds__(256) void bn_lif_flag(const float* __restrict__ Y, const double* __restrict__ stats,
                                                   const double* __restrict__ wn, const double* __restrict__ xn,
                                                   double K, void* __restrict__ sout,
                                                   uint* __restrict__ list, int* __restrict__ cnt){
  const int idx = blockIdx.x*256 + threadIdx.x;
  const int n = idx & 255, o = (idx>>8) & 511, b = idx>>17;
  const double scale = stats[o], shift = stats[512+o];
  const double kw = K * fabs(scale) * wn[o];
  double v = 0.0, minm = 1e300, bmax = 0.0;
  #pragma unroll
  for (int t=0;t<4;++t){
    const int g = t*16+b;
    const size_t ii = ((size_t)g*512+o)*256 + n;
    double y = (double)Y[ii];
    double Bnd = kw * xn[g*256+n]; bmax = fmax(bmax, Bnd);
    double z = y*scale + shift;
    v = v + (z - v)*0.5;
    double m = fabs(v - 1.0) - 2.0*bmax;
    minm = fmin(minm, m);
    bool sp = (v - 1.0) >= 0.0;
    if (OUTF) ((float*)sout)[ii] = sp ? 1.0f : 0.0f;
    else      ((u8*)sout)[ii]    = sp ? 1 : 0;
    if (sp) v = 0.0;
  }
  if (minm < 0.0){
    int pos = atomicAdd(cnt, 1);
    if (pos < CAP) list[pos] = ((uint)b<<17)|((uint)o<<8)|(uint)n;
  }
}

// fp64 exact recompute of flagged cells. Xn layout [g][n][c]: f32 (OUTF=0) / u8 (OUTF=1).
template<int OUTF>
__global__ __launch_bounds__(256) void recompute(const uint* __restrict__ list, const int* __restrict__ cnt,
                                                 const float* __restrict__ W, const void* __restrict__ Xn,
                                                 const double* __restrict__ stats, void* __restrict__ out){
  const int lane = threadIdx.x & 63;
  const int wv = blockIdx.x*4 + (threadIdx.x>>6);
  int ne = *cnt; if (ne > CAP) ne = CAP;
  for (int e = wv; e < ne; e += gridDim.x*4){
    const uint code = list[e];
    const int b = code>>17, o = (code>>8)&511, n = code&255;
    if (b > 15) continue;
    const double scale = stats[o], shift = stats[512+o];
    double v = 0.0;
    for (int t=0;t<4;++t){
      const int g = t*16+b;
      double y = 0.0;
      #pragma unroll
      for (int i=0;i<8;++i){
        int c = lane + 64*i;
        double w = (double)W[(size_t)o*512 + c];
        double xv;
        if (OUTF) xv = (double)((const u8*)Xn)[((size_t)g*256+n)*512 + c];
        else      xv = (double)((const float*)Xn)[((size_t)g*256+n)*512 + c];
        y = fma(w, xv, y);
      }
      #pragma unroll
      for (int off=32; off>0; off>>=1) y += __shfl_xor(y, off);
      double z = y*scale + shift;
      v = v + (z - v)*0.5;
      bool sp = (v - 1.0) >= 0.0;
      if (lane==0){
        const size_t ii = ((size_t)g*512+o)*256 + n;
        if (OUTF) ((float*)out)[ii] = sp ? 1.0f : 0.0f;
        else      ((u8*)out)[ii]    = sp ? 1 : 0;
      }
      if (sp) v = 0.0;
    }
  }
}

// ---------------------------------------------------------------------------
// LIF (fp64) for the attention values, theta=0.5, exact (dyadic inputs).
// ---------------------------------------------------------------------------
__global__ __launch_bounds__(256) void lif_kernel(const float* __restrict__ Y, double thresh,
                                                  u8* __restrict__ s_u8){
  const size_t idx = (size_t)blockIdx.x * 256 + threadIdx.x;
  double v = 0.0;
  #pragma unroll
  for (int t = 0; t < 4; ++t){
    double z = (double)Y[(size_t)t * BCN + idx];
    v = v + (z - v) * 0.5;
    bool sp = (v - thresh) >= 0.0;
    s_u8[(size_t)t * BCN + idx] = sp ? 1 : 0;
    if (sp) v = 0.0;
  }
}

// ---------------------------------------------------------------------------
// kv[d][e] = sum_n k v  (integer, exact)
// ---------------------------------------------------------------------------
__global__ __launch_bounds__(256) void attn_kv(const u8* __restrict__ sk, const u8* __restrict__ sv,
                                               float* __restrict__ kv){
  const int blk = blockIdx.x;
  const int tid = threadIdx.x;
  const size_t base = ((size_t)(blk >> 3) * 512 + (size_t)(blk & 7) * 64) * 256;
  __shared__ u8 kS[64][256];
  __shared__ u8 vS[64][256];
  const uint32_t* K32 = (const uint32_t*)(sk + base);
  const uint32_t* V32 = (const uint32_t*)(sv + base);
  uint32_t* kS32 = (uint32_t*)&kS[0][0];
  uint32_t* vS32 = (uint32_t*)&vS[0][0];
  #pragma unroll
  for (int i = 0; i < 16; ++i){ kS32[i*256+tid] = K32[i*256+tid]; vS32[i*256+tid] = V32[i*256+tid]; }
  __syncthreads();
  const int d0 = (tid >> 4) << 2, e0 = (tid & 15) << 2;
  int acc[4][4] = {};
  for (int n = 0; n < 256; ++n){
    int k_[4], v_[4];
    #pragma unroll
    for (int i = 0; i < 4; ++i) k_[i] = kS[d0+i][n];
    #pragma unroll
    for (int j = 0; j < 4; ++j) v_[j] = vS[e0+j][n];
    #pragma unroll
    for (int i = 0; i < 4; ++i)
      #pragma unroll
      for (int j = 0; j < 4; ++j) acc[i][j] += k_[i]*v_[j];
  }
  float* KV = kv + (size_t)blk * 4096;
  #pragma unroll
  for (int i = 0; i < 4; ++i)
    #pragma unroll
    for (int j = 0; j < 4; ++j) KV[(d0+i)*64 + e0+j] = (float)acc[i][j];
}

__global__ __launch_bounds__(256) void attn_qkv(const u8* __restrict__ sq, const float* __restrict__ kv,
                                                float* __restrict__ attn){
  const int blk = blockIdx.x;
  const int tid = threadIdx.x;
  const size_t base = ((size_t)(blk >> 3) * 512 + (size_t)(blk & 7) * 64) * 256;
  __shared__ u8 qS[64][256];
  __shared__ float kvS[64][64];
  const uint32_t* Q32 = (const uint32_t*)(sq + base);
  uint32_t* qS32 = (uint32_t*)&qS[0][0];
  const float* KV = kv + (size_t)blk * 4096;
  #pragma unroll
  for (int i = 0; i < 16; ++i){
    qS32[i*256+tid] = Q32[i*256+tid];
    (&kvS[0][0])[i*256+tid] = KV[i*256+tid];
  }
  __syncthreads();
  const int n = tid;
  float acc[64];
  #pragma unroll
  for (int e = 0; e < 64; ++e) acc[e] = 0.0f;
  for (int d = 0; d < 64; ++d){
    float qf = (float)qS[d][n];
    #pragma unroll
    for (int e = 0; e < 64; ++e) acc[e] = fmaf(qf, kvS[d][e], acc[e]);
  }
  float* A = attn + base;
  #pragma unroll
  for (int e = 0; e < 64; ++e) A[(size_t)e*256 + n] = acc[e]*0.125f;
}

// ---------------------------------------------------------------------------
extern "C" void kernel_launch(void* const* d_in, const int* in_sizes, int n_in,
                              void* d_out, int out_size, void* d_ws, size_t ws_size,
                              hipStream_t stream){
  const float* x       = (const float*)d_in[0];
  const float* Wb[4]   = {(const float*)d_in[1], (const float*)d_in[4], (const float*)d_in[7], (const float*)d_in[10]};
  const float* Gm[4]   = {(const float*)d_in[2], (const float*)d_in[5], (const float*)d_in[8], (const float*)d_in[12]};
  const float* Bt[4]   = {(const float*)d_in[3], (const float*)d_in[6], (const float*)d_in[9], (const float*)d_in[13]};
  // d_in[11] = proj_b: cancels exactly inside training-mode BN -> unused.

  char* p = (char*)d_ws;
  float* yA   = (float*)p;            p += 33554432;   // conv out; also aliased: Gpart (f64, 33.5MB) early, Gspart (f32, 16.8MB) pre-proj
  u8* s_q     = (u8*)p;               p += 8388608;
  u8* s_k     = (u8*)p;               p += 8388608;
  u8* s_v     = (u8*)p;               p += 8388608;
  u8* s_at    = (u8*)p;               p += 8388608;
  float* XT32 = (float*)p;
  u8* sT      = (u8*)p;               p += 33554432;   // sT aliases XT32 (XT32 dead before proj)
  ushort* Whl = (ushort*)p;           p += 4194304;    // [4 mats][hi 262144 | lo 262144] ushorts
  float* kvb  = (float*)p;            p += 8388608;
  double* G   = (double*)p;           p += 2097152;
  float* Gs   = (float*)p;            p += 1048576;
  double* M   = (double*)p;           p += 2097152;
  double* colsumX = (double*)p;       p += 4096;
  double* colsumS = (double*)p;       p += 4096;
  double* xnorm   = (double*)p;       p += 131072;
  double* snorm   = (double*)p;       p += 131072;
  double* wn      = (double*)p;       p += 16384;      // [4][512]
  double* stats   = (double*)p;       p += 32768;      // [4][1024]
  int*    cnt     = (int*)p;          p += 256;
  uint*   lists   = (uint*)p;         p += 4*CAP*4;    // [4][CAP] uints
  const size_t NEED = (size_t)(p - (char*)d_ws);

  double* Gpart  = (double*)yA;   // 16 x 512x512 fp64 = 33.5 MB (yA dead until first fgemm)
  float*  Gspart = (float*)yA;    // 16 x 512x512 f32  = 16.8 MB (yA dead during proj-gram)

  if (ws_size < NEED){
    guard_fill<<<(out_size+255)/256, 256, 0, stream>>>((float*)d_out, out_size);
    return;
  }

  const double K0 = 4.0e-5;   // qkv fast-path bound const (~6x expected-max err)
  const double K1 = 4.0e-5;   // proj (B exact 0/1)

  hipMemsetAsync(cnt, 0, 256, stream);

  for (int i=0;i<4;++i){
    w_split<<<1024, 256, 0, stream>>>(Wb[i], Whl + (size_t)i*524288, Whl + (size_t)i*524288 + 262144);
    wnorm_k<<<512, 256, 0, stream>>>(Wb[i], wn + i*512);
  }
  xtrans32<<<dim3(4,8,64), 256, 0, stream>>>(x, XT32);
  colsum_k<float><<<512, 256, 0, stream>>>(x, colsumX);
  norm_k<float><<<64, 256, 0, stream>>>(x, xnorm);
  gramx2<<<dim3(8,8,16), 256, 0, stream>>>(x, Gpart);
  greduce64<<<1024, 256, 0, stream>>>(Gpart, G);

  u8* sOut[3] = {s_q, s_k, s_v};
  for (int i=0;i<3;++i){
    hipMemsetAsync(M, 0, 2097152, stream);
    mgemm<double><<<dim3(8,8,4), 256, 0, stream>>>(Wb[i], G, M);
    finalize_stats<<<512, 256, 0, stream>>>(Wb[i], M, colsumX, Gm[i], Bt[i], stats + i*1024);
    fgemm<0><<<dim3(2,4,64), 256, 0, stream>>>(Whl + (size_t)i*524288, Whl + (size_t)i*524288 + 262144, XT32, yA);
    bn_lif_flag<0><<<8192, 256, 0, stream>>>(yA, stats + i*1024, wn + i*512, xnorm, K0,
                                             sOut[i], lists + (size_t)i*CAP, cnt + i);
    recompute<0><<<512, 256, 0, stream>>>(lists + (size_t)i*CAP, cnt + i, Wb[i], XT32, stats + i*1024, sOut[i]);
  }

  attn_kv<<<512, 256, 0, stream>>>(s_k, s_v, kvb);
  attn_qkv<<<512, 256, 0, stream>>>(s_q, kvb, yA);
  lif_kernel<<<8192, 256, 0, stream>>>(yA, 0.5, s_at);

  u8_trans<<<dim3(4,8,64), 256, 0, stream>>>(s_at, sT);
  colsum_k<u8><<<512, 256, 0, stream>>>(s_at, colsumS);
  norm_k<u8><<<64, 256, 0, stream>>>(s_at, snorm);
  sgram<<<dim3(4,4,16), 256, 0, stream>>>(s_at, Gspart);
  greduceS<<<1024, 256, 0, stream>>>(Gspart, Gs);

  hipMemsetAsync(M, 0, 2097152, stream);
  mgemm<float><<<dim3(8,8,4), 256, 0, stream>>>(Wb[3], Gs, M);
  finalize_stats<<<512, 256, 0, stream>>>(Wb[3], M, colsumS, Gm[3], Bt[3], stats + 3*1024);
  fgemm<1><<<dim3(2,4,64), 256, 0, stream>>>(Whl + (size_t)3*524288, Whl + (size_t)3*524288 + 262144, sT, yA);
  bn_lif_flag<1><<<8192, 256, 0, stream>>>(yA, stats + 3*1024, wn + 3*512, snorm, K1,
                                           d_out, lists + (size_t)3*CAP, cnt + 3);
  recompute<1><<<512, 256, 0, stream>>>(lists + (size_t)3*CAP, cnt + 3, Wb[3], sT, stats + 3*1024, d_out);
}

// Round 9
// 1006.213 us; speedup vs baseline: 2.1037x; 1.0425x over previous
//
#include <hip/hip_runtime.h>
#include <hip/hip_bf16.h>
#include <stdint.h>

// Dims: T=4, B=16, C=512, N=256 (16x16). heads=8, d=64. groups g = t*16+b (64).
#define BCN  (16*512*256)
#define CN   (512*256)
#define NG   64
#define CAP  65536

typedef __attribute__((ext_vector_type(8))) short bf16x8;
typedef __attribute__((ext_vector_type(4))) float f32x4;
typedef __attribute__((ext_vector_type(4))) int   int4v;
typedef unsigned char u8;

__device__ inline ushort f2bf(float x){ union{ __hip_bfloat16 b; ushort u; } z; z.b = __float2bfloat16(x); return z.u; }
__device__ inline float  bf2f(ushort u){ union{ uint i; float f; } z; z.i = (uint)u<<16; return z.f; }

__device__ inline double blk_reduce(double v, double* sh){
  int tid = threadIdx.x; sh[tid] = v; __syncthreads();
  for (int off=128; off>0; off>>=1){ if (tid<off) sh[tid]+=sh[tid+off]; __syncthreads(); }
  double r = sh[0]; __syncthreads(); return r;
}

// ---------------------------------------------------------------------------
__global__ __launch_bounds__(256) void guard_fill(float* out, int n){
  int i = blockIdx.x*256+threadIdx.x; if (i<n) out[i] = -1.0f;
}

// W (f32 [o][c]) -> Whi/Wlo bf16 [o][c]
__global__ __launch_bounds__(256) void w_split(const float* __restrict__ W,
                                               ushort* __restrict__ Whi, ushort* __restrict__ Wlo){
  int i = blockIdx.x*256+threadIdx.x; if (i >= 512*512) return;
  float x = W[i]; ushort h = f2bf(x);
  Whi[i] = h; Wlo[i] = f2bf(x - bf2f(h));
}

// ||W[o,:]||_2 fp64
__global__ __launch_bounds__(256) void wnorm_k(const float* __restrict__ W, double* __restrict__ wn){
  __shared__ double sh[256];
  int o = blockIdx.x;
  double s = 0.0;
  for (int c = threadIdx.x; c < 512; c += 256){ double w = (double)W[o*512+c]; s += w*w; }
  double t = blk_reduce(s, sh);
  if (threadIdx.x==0) wn[o] = sqrt(t);
}

// X [g][c][n] f32 -> XT32 [g][n][c] f32   (64x64 tiles)
__global__ __launch_bounds__(256) void xtrans32(const float* __restrict__ X, float* __restrict__ XT){
  __shared__ float lds[64][65];
  const int g = blockIdx.z, c0 = blockIdx.y<<6, n0 = blockIdx.x<<6;
  const int t = threadIdx.x, r = t>>2, q = t&3;
  #pragma unroll
  for (int u4=0; u4<4; ++u4){
    f32x4 v = *(const f32x4*)&X[((size_t)g*512 + c0 + r)*256 + n0 + q*16 + u4*4];
    lds[r][q*16+u4*4+0]=v.x; lds[r][q*16+u4*4+1]=v.y; lds[r][q*16+u4*4+2]=v.z; lds[r][q*16+u4*4+3]=v.w;
  }
  __syncthreads();
  #pragma unroll
  for (int u4=0; u4<4; ++u4){
    f32x4 o;
    o.x = lds[q*16+u4*4+0][r]; o.y = lds[q*16+u4*4+1][r];
    o.z = lds[q*16+u4*4+2][r]; o.w = lds[q*16+u4*4+3][r];
    *(f32x4*)&XT[((size_t)g*256 + n0 + r)*512 + c0 + q*16 + u4*4] = o;
  }
}

// s_at [g][c][n] u8 -> sT [g][n][c] u8
__global__ __launch_bounds__(256) void u8_trans(const u8* __restrict__ S, u8* __restrict__ ST){
  __shared__ u8 lds[64][65];
  const int g = blockIdx.z, c0 = blockIdx.y<<6, n0 = blockIdx.x<<6;
  const int t = threadIdx.x, r = t>>2, q = t&3;
  int4v v = *(const int4v*)&S[((size_t)g*512 + c0 + r)*256 + n0 + q*16];
  const u8* pb = (const u8*)&v;
  #pragma unroll
  for (int u=0; u<16; ++u) lds[r][q*16+u] = pb[u];
  __syncthreads();
  u8 ob[16];
  #pragma unroll
  for (int u=0; u<16; ++u) ob[u] = lds[q*16+u][r];
  *(int4v*)&ST[((size_t)g*256 + n0 + r)*512 + c0 + q*16] = *(int4v*)ob;
}

// colsum over (g,n) per c, fp64
template<typename T>
__global__ __launch_bounds__(256) void colsum_k(const T* __restrict__ X, double* __restrict__ cs){
  __shared__ double sh[256];
  const int c = blockIdx.x;
  double s = 0.0;
  for (int g=0; g<NG; ++g) s += (double)X[((size_t)g*512+c)*256 + threadIdx.x];
  double t = blk_reduce(s, sh);
  if (threadIdx.x==0) cs[c] = t;
}

// per-(g,n) column 2-norm over c, fp64. 256 blocks = (g, n-quarter).
template<typename T>
__global__ __launch_bounds__(256) void norm_k2(const T* __restrict__ X, double* __restrict__ nrm){
  __shared__ double sh[4][64];
  const int g = blockIdx.x>>2, nq = blockIdx.x&3;
  const int nl = threadIdx.x&63, cg = threadIdx.x>>6;
  const int n = nq*64 + nl;
  double s = 0.0;
  #pragma unroll 4
  for (int c=cg; c<512; c+=4){
    double v = (double)X[((size_t)g*512+c)*256 + n]; s += v*v;
  }
  sh[cg][nl] = s; __syncthreads();
  if (cg==0) nrm[g*256+n] = sqrt(sh[0][nl]+sh[1][nl]+sh[2][nl]+sh[3][nl]);
}

// ---------------------------------------------------------------------------
// gramx2t: triangular Gram. Gpart[z][ci][cj] over 36 lower-tri 64-tile pairs,
// mirror-stored. acc 4x4 fp64 (no spill), NON-atomic per-slice partials.
// grid (36, 16).
// ---------------------------------------------------------------------------
__global__ __launch_bounds__(256, 4) void gramx2t(const float* __restrict__ X, double* __restrict__ Gpart){
  const int ti_tab[36] = {0,1,1,2,2,2,3,3,3,3,4,4,4,4,4,5,5,5,5,5,5,6,6,6,6,6,6,6,7,7,7,7,7,7,7,7};
  const int tj_tab[36] = {0,0,1,0,1,2,0,1,2,3,0,1,2,3,4,0,1,2,3,4,5,0,1,2,3,4,5,6,0,1,2,3,4,5,6,7};
  const int p = blockIdx.x, z = blockIdx.y;
  const int ci0 = ti_tab[p]<<6, cj0 = tj_tab[p]<<6;
  const bool offd = (ci0 != cj0);
  const int tid = threadIdx.x, tx = tid&15, ty = tid>>4;
  __shared__ float A[64][68];
  __shared__ float B[64][68];
  double acc[4][4] = {};

  for (int gg=0; gg<4; ++gg){
    const int g = z*4+gg;
    for (int nc=0; nc<4; ++nc){
      const int n0 = nc<<6;
      __syncthreads();
      { const int r = tid>>2, q = tid&3;
        #pragma unroll
        for (int u=0; u<4; ++u){
          f32x4 va = *(const f32x4*)&X[((size_t)g*512 + ci0 + r)*256 + n0 + q*16 + u*4];
          A[q*16+u*4+0][r]=va.x; A[q*16+u*4+1][r]=va.y; A[q*16+u*4+2][r]=va.z; A[q*16+u*4+3][r]=va.w;
          f32x4 vb = *(const f32x4*)&X[((size_t)g*512 + cj0 + r)*256 + n0 + q*16 + u*4];
          B[q*16+u*4+0][r]=vb.x; B[q*16+u*4+1][r]=vb.y; B[q*16+u*4+2][r]=vb.z; B[q*16+u*4+3][r]=vb.w;
        }
      }
      __syncthreads();
      #pragma unroll 8
      for (int n=0; n<64; ++n){
        const f32x4 af = *(const f32x4*)&A[n][ty*4];
        const f32x4 bf = *(const f32x4*)&B[n][tx*4];
        double a[4] = {(double)af.x,(double)af.y,(double)af.z,(double)af.w};
        double b[4] = {(double)bf.x,(double)bf.y,(double)bf.z,(double)bf.w};
        #pragma unroll
        for (int i=0;i<4;++i)
          #pragma unroll
          for (int j=0;j<4;++j) acc[i][j] = fma(a[i], b[j], acc[i][j]);
      }
    }
  }
  double* Gp = Gpart + (size_t)z*262144;
  #pragma unroll
  for (int i=0;i<4;++i)
    #pragma unroll
    for (int j=0;j<4;++j){
      Gp[(size_t)(ci0+ty*4+i)*512 + cj0+tx*4+j] = acc[i][j];
      if (offd) Gp[(size_t)(cj0+tx*4+j)*512 + ci0+ty*4+i] = acc[i][j];
    }
}

__global__ __launch_bounds__(256) void greduce64(const double* __restrict__ Gpart, double* __restrict__ G){
  const int i = blockIdx.x*256 + threadIdx.x;      // 262144
  double s = 0.0;
  #pragma unroll
  for (int z=0; z<16; ++z) s += Gpart[(size_t)z*262144 + i];
  G[i] = s;
}

__global__ __launch_bounds__(256) void greduceS(const float* __restrict__ Gspart, float* __restrict__ Gs){
  const int i = blockIdx.x*256 + threadIdx.x;
  float s = 0.0f;
  #pragma unroll
  for (int z=0; z<16; ++z) s += Gspart[(size_t)z*262144 + i];
  Gs[i] = s;
}

// ---------------------------------------------------------------------------
// M[o][c'] = sum_k W[o][k] G[k][c']  fp64, k-sliced over blockIdx.z + atomics
// ---------------------------------------------------------------------------
template<typename GT>
__global__ __launch_bounds__(256) void mgemm(const float* __restrict__ W, const GT* __restrict__ G,
                                             double* __restrict__ M){
  const int o0 = blockIdx.y<<6, c0 = blockIdx.x<<6;
  const int k0base = blockIdx.z*128;
  __shared__ float  wT[32][68];
  __shared__ double gS[32][66];
  double acc[4][4];
  #pragma unroll
  for (int i=0;i<4;++i)
    #pragma unroll
    for (int j=0;j<4;++j) acc[i][j]=0.0;
  const int tid = threadIdx.x, tx = tid&15, ty = tid>>4;

  for (int kc=0; kc<4; ++kc){
    const int k0 = k0base + kc*32;
    __syncthreads();
    { int r = tid>>2, q = tid&3;  // W: 64o x 32k -> wT[k][o]
      f32x4 w0 = *(const f32x4*)&W[(size_t)(o0+r)*512 + k0 + q*8];
      f32x4 w1 = *(const f32x4*)&W[(size_t)(o0+r)*512 + k0 + q*8 + 4];
      wT[q*8+0][r]=w0.x; wT[q*8+1][r]=w0.y; wT[q*8+2][r]=w0.z; wT[q*8+3][r]=w0.w;
      wT[q*8+4][r]=w1.x; wT[q*8+5][r]=w1.y; wT[q*8+6][r]=w1.z; wT[q*8+7][r]=w1.w;
      int k = tid>>3, h = tid&7;  // G rows: 32k x 64c
      #pragma unroll
      for (int u=0;u<8;++u) gS[k][h*8+u] = (double)G[(size_t)(k0+k)*512 + c0 + h*8 + u];
    }
    __syncthreads();
    #pragma unroll
    for (int k=0;k<32;++k){
      f32x4 aw = *(const f32x4*)&wT[k][ty*4];
      double a[4] = {(double)aw.x,(double)aw.y,(double)aw.z,(double)aw.w};
      double b[4];
      #pragma unroll
      for (int j=0;j<4;++j) b[j] = gS[k][tx*4+j];
      #pragma unroll
      for (int i=0;i<4;++i)
        #pragma unroll
        for (int j=0;j<4;++j) acc[i][j] = fma(a[i], b[j], acc[i][j]);
    }
  }
  #pragma unroll
  for (int i=0;i<4;++i)
    #pragma unroll
    for (int j=0;j<4;++j)
      atomicAdd(&M[(size_t)(o0+ty*4+i)*512 + c0+tx*4+j], acc[i][j]);
}

// stats: scale[o] = gamma*rsqrt(var+eps), shift[o] = beta - mean*scale
__global__ __launch_bounds__(256) void finalize_stats(const float* __restrict__ W, const double* __restrict__ M,
                                                      const double* __restrict__ cs,
                                                      const float* __restrict__ gamma, const float* __restrict__ beta,
                                                      double* __restrict__ stats){
  __shared__ double sh[256];
  const int o = blockIdx.x;
  double s1=0.0, s2=0.0;
  for (int c = threadIdx.x; c < 512; c += 256){
    double w = (double)W[(size_t)o*512+c];
    s1 += w*cs[c]; s2 += w*M[(size_t)o*512+c];
  }
  double t1 = blk_reduce(s1, sh);
  double t2 = blk_reduce(s2, sh);
  if (threadIdx.x==0){
    double mean = t1*(1.0/16384.0);
    double var  = t2*(1.0/16384.0) - mean*mean;
    double sc = (double)gamma[o] / sqrt(var + 1e-5);
    stats[o] = sc; stats[512+o] = (double)beta[o] - mean*sc;
  }
}

// ---------------------------------------------------------------------------
// Fast bf16-MFMA GEMM. MODE 0: A=Whi/Wlo, B=XT32 f32 (split in staging, 3 prod)
//                      MODE 1: A=Whi/Wlo, B=sT u8 spikes (exact, 2 products)
// ---------------------------------------------------------------------------
template<int MODE>
__global__ __launch_bounds__(256) void fgemm(const ushort* __restrict__ Ahi, const ushort* __restrict__ Alo,
                                             const void* __restrict__ Bsrc, float* __restrict__ Y){
  const int g = blockIdx.z, o0 = blockIdx.y<<7, n0 = blockIdx.x<<7;
  const int tid = threadIdx.x, lane = tid&63, wv = tid>>6;
  const int wo = (wv>>1)<<6, wn2 = (wv&1)<<6;
  const int l15 = lane&15, l4 = lane>>4, ss = l4 ^ (lane&3);
  __shared__ __align__(16) ushort L[4][128][32];
  f32x4 acc[4][4];
  #pragma unroll
  for (int i=0;i<4;++i)
    #pragma unroll
    for (int j=0;j<4;++j) acc[i][j] = f32x4{0.f,0.f,0.f,0.f};

  for (int c0=0; c0<512; c0+=32){
    __syncthreads();
    #pragma unroll
    for (int s2=0; s2<2; ++s2){
      int S = tid*2+s2, r = S>>2, q = S&3, qq = q ^ (r&3);
      *(int4v*)&L[0][r][qq*8] = *(const int4v*)&Ahi[(size_t)(o0+r)*512 + c0 + q*8];
      *(int4v*)&L[1][r][qq*8] = *(const int4v*)&Alo[(size_t)(o0+r)*512 + c0 + q*8];
      if (MODE==0){
        const float* B = (const float*)Bsrc;
        f32x4 x0 = *(const f32x4*)&B[((size_t)g*256 + n0 + r)*512 + c0 + q*8];
        f32x4 x1 = *(const f32x4*)&B[((size_t)g*256 + n0 + r)*512 + c0 + q*8 + 4];
        union { ushort us[8]; int4v v; } hiU, loU;
        float xv[8] = {x0.x,x0.y,x0.z,x0.w,x1.x,x1.y,x1.z,x1.w};
        #pragma unroll
        for (int u=0;u<8;++u){ ushort h = f2bf(xv[u]); hiU.us[u]=h; loU.us[u]=f2bf(xv[u]-bf2f(h)); }
        *(int4v*)&L[2][r][qq*8] = hiU.v;
        *(int4v*)&L[3][r][qq*8] = loU.v;
      } else {
        const u8* B = (const u8*)Bsrc;
        uint2 raw = *(const uint2*)&B[((size_t)g*256 + n0 + r)*512 + c0 + q*8];
        union { ushort us[8]; int4v v; } hiU;
        #pragma unroll
        for (int u=0;u<4;++u) hiU.us[u]   = ((raw.x>>(8*u))&255u) ? 0x3F80 : 0;
        #pragma unroll
        for (int u=0;u<4;++u) hiU.us[4+u] = ((raw.y>>(8*u))&255u) ? 0x3F80 : 0;
        *(int4v*)&L[2][r][qq*8] = hiU.v;
      }
    }
    __syncthreads();
    bf16x8 ah[4], al[4], bh[4], bl[4];
    #pragma unroll
    for (int f=0; f<4; ++f){
      int ra = wo + f*16 + l15;
      ah[f] = *(const bf16x8*)&L[0][ra][ss*8];
      al[f] = *(const bf16x8*)&L[1][ra][ss*8];
      int rb = wn2 + f*16 + l15;
      bh[f] = *(const bf16x8*)&L[2][rb][ss*8];
      if (MODE==0) bl[f] = *(const bf16x8*)&L[3][rb][ss*8];
    }
    #pragma unroll
    for (int of=0; of<4; ++of)
      #pragma unroll
      for (int nf=0; nf<4; ++nf){
        acc[of][nf] = __builtin_amdgcn_mfma_f32_16x16x32_bf16(ah[of], bh[nf], acc[of][nf], 0,0,0);
        acc[of][nf] = __builtin_amdgcn_mfma_f32_16x16x32_bf16(al[of], bh[nf], acc[of][nf], 0,0,0);
        if (MODE==0)
          acc[of][nf] = __builtin_amdgcn_mfma_f32_16x16x32_bf16(ah[of], bl[nf], acc[of][nf], 0,0,0);
      }
  }
  #pragma unroll
  for (int of=0; of<4; ++of)
    #pragma unroll
    for (int nf=0; nf<4; ++nf){
      #pragma unroll
      for (int r=0;r<4;++r){
        int o = o0 + wo + of*16 + l4*4 + r;
        int n = n0 + wn2 + nf*16 + l15;
        Y[((size_t)g*512 + o)*256 + n] = acc[of][nf][r];
      }
    }
}

// ---------------------------------------------------------------------------
// Spike Gram via MFMA (exact integer counts in fp32), NON-atomic per-slice
// partials Gspart[16][512x512].
// ---------------------------------------------------------------------------
__global__ __launch_bounds__(256) void sgram(const u8* __restrict__ S, float* __restrict__ Gspart){
  const int ci0 = blockIdx.x<<7, cj0 = blockIdx.y<<7, slice = blockIdx.z; // 16 slices x 4 g
  const int tid = threadIdx.x, lane = tid&63, wv = tid>>6;
  const int wo = (wv>>1)<<6, wn2 = (wv&1)<<6;
  const int l15 = lane&15, l4 = lane>>4, ss = l4 ^ (lane&3);
  __shared__ __align__(16) ushort L[2][128][32];
  f32x4 acc[4][4];
  #pragma unroll
  for (int i=0;i<4;++i)
    #pragma unroll
    for (int j=0;j<4;++j) acc[i][j] = f32x4{0.f,0.f,0.f,0.f};

  for (int gg=0; gg<4; ++gg){
    const int g = slice*4+gg;
    for (int nc=0; nc<8; ++nc){
      const int n0 = nc*32;
      __syncthreads();
      #pragma unroll
      for (int s2=0; s2<2; ++s2){
        int Sl = tid*2+s2, r = Sl>>2, q = Sl&3, qq = q ^ (r&3);
        uint2 ra = *(const uint2*)&S[((size_t)g*512 + ci0 + r)*256 + n0 + q*8];
        uint2 rb = *(const uint2*)&S[((size_t)g*512 + cj0 + r)*256 + n0 + q*8];
        union { ushort us[8]; int4v v; } A, Bv;
        #pragma unroll
        for (int u=0;u<4;++u){ A.us[u]   = ((ra.x>>(8*u))&255u)?0x3F80:0; Bv.us[u]   = ((rb.x>>(8*u))&255u)?0x3F80:0; }
        #pragma unroll
        for (int u=0;u<4;++u){ A.us[4+u] = ((ra.y>>(8*u))&255u)?0x3F80:0; Bv.us[4+u] = ((rb.y>>(8*u))&255u)?0x3F80:0; }
        *(int4v*)&L[0][r][qq*8] = A.v;
        *(int4v*)&L[1][r][qq*8] = Bv.v;
      }
      __syncthreads();
      bf16x8 af[4], bfv[4];
      #pragma unroll
      for (int f=0; f<4; ++f){
        int ra = wo + f*16 + l15;  af[f]  = *(const bf16x8*)&L[0][ra][ss*8];
        int rb = wn2 + f*16 + l15; bfv[f] = *(const bf16x8*)&L[1][rb][ss*8];
      }
      #pragma unroll
      for (int of=0; of<4; ++of)
        #pragma unroll
        for (int nf=0; nf<4; ++nf)
          acc[of][nf] = __builtin_amdgcn_mfma_f32_16x16x32_bf16(af[of], bfv[nf], acc[of][nf], 0,0,0);
    }
  }
  float* Gp = Gspart + (size_t)slice*262144;
  #pragma unroll
  for (int of=0; of<4; ++of)
    #pragma unroll
    for (int nf=0; nf<4; ++nf)
      #pragma unroll
      for (int r=0;r<4;++r){
        int ci = ci0 + wo + of*16 + l4*4 + r;
        int cj = cj0 + wn2 + nf*16 + l15;
        Gp[(size_t)ci*512 + cj] = acc[of][nf][r];
      }
}

// ---------------------------------------------------------------------------
// BN-affine (fp64 stats) + LIF (theta=1) + spike write + near-margin flagging.
// ---------------------------------------------------------------------------
template<int OUTF>
__global__ __launch_bounds__(256) void bn_lif_flag(const float* __restrict__ Y, const double* __restrict__ stats,
                                                   const double* __restrict__ wn, const double* __restrict__ xn,
                                                   double K, void* __restrict__ sout,
                                                   uint* __restrict__ list, int* __restrict__ cnt){
  const int idx = blockIdx.x*256 + threadIdx.x;
  const int n = idx & 255, o = (idx>>8) & 511, b = idx>>17;
  const double scale = stats[o], shift = stats[512+o];
  const double kw = K * fabs(scale) * wn[o];
  double v = 0.0, minm = 1e300, bmax = 0.0;
  #pragma unroll
  for (int t=0;t<4;++t){
    const int g = t*16+b;
    const size_t ii = ((size_t)g*512+o)*256 + n;
    double y = (double)Y[ii];
    double Bnd = kw * xn[g*256+n]; bmax = fmax(bmax, Bnd);
    double z = y*scale + shift;
    v = v + (z - v)*0.5;
    double m = fabs(v - 1.0) - 2.0*bmax;
    minm = fmin(minm, m);
    bool sp = (v - 1.0) >= 0.0;
    if (OUTF) ((float*)sout)[ii] = sp ? 1.0f : 0.0f;
    else      ((u8*)sout)[ii]    = sp ? 1 : 0;
    if (sp) v = 0.0;
  }
  if (minm < 0.0){
    int pos = atomicAdd(cnt, 1);
    if (pos < CAP) list[pos] = ((uint)b<<17)|((uint)o<<8)|(uint)n;
  }
}

// fp64 exact recompute of flagged cells. Xn layout [g][n][c]: f32 (OUTF=0) / u8 (OUTF=1).
template<int OUTF>
__global__ __launch_bounds__(256) void recompute(const uint* __restrict__ list, const int* __restrict__ cnt,
                                                 const float* __restrict__ W, const void* __restrict__ Xn,
                                                 const double* __restrict__ stats, void* __restrict__ out){
  const int lane = threadIdx.x & 63;
  const int wv = blockIdx.x*4 + (threadIdx.x>>6);
  int ne = *cnt; if (ne > CAP) ne = CAP;
  for (int e = wv; e < ne; e += gridDim.x*4){
    const uint code = list[e];
    const int b = code>>17, o = (code>>8)&511, n = code&255;
    if (b > 15) continue;
    const double scale = stats[o], shift = stats[512+o];
    double v = 0.0;
    for (int t=0;t<4;++t){
      const int g = t*16+b;
      double y = 0.0;
      #pragma unroll
      for (int i=0;i<8;++i){
        int c = lane + 64*i;
        double w = (double)W[(size_t)o*512 + c];
        double xv;
        if (OUTF) xv = (double)((const u8*)Xn)[((size_t)g*256+n)*512 + c];
        else      xv = (double)((const float*)Xn)[((size_t)g*256+n)*512 + c];
        y = fma(w, xv, y);
      }
      #pragma unroll
      for (int off=32; off>0; off>>=1) y += __shfl_xor(y, off);
      double z = y*scale + shift;
      v = v + (z - v)*0.5;
      bool sp = (v - 1.0) >= 0.0;
      if (lane==0){
        const size_t ii = ((size_t)g*512+o)*256 + n;
        if (OUTF) ((float*)out)[ii] = sp ? 1.0f : 0.0f;
        else      ((u8*)out)[ii]    = sp ? 1 : 0;
      }
      if (sp) v = 0.0;
    }
  }
}

// ---------------------------------------------------------------------------
// LIF (fp64) for the attention values, theta=0.5, exact (dyadic inputs).
// ---------------------------------------------------------------------------
__global__ __launch_bounds__(256) void lif_kernel(const float* __restrict__ Y, double thresh,
                                                  u8* __restrict__ s_u8){
  const size_t idx = (size_t)blockIdx.x * 256 + threadIdx.x;
  double v = 0.0;
  #pragma unroll
  for (int t = 0; t < 4; ++t){
    double z = (double)Y[(size_t)t * BCN + idx];
    v = v + (z - v) * 0.5;
    bool sp = (v - thresh) >= 0.0;
    s_u8[(size_t)t * BCN + idx] = sp ? 1 : 0;
    if (sp) v = 0.0;
  }
}

// ---------------------------------------------------------------------------
// kv[d][e] = sum_n k v  (integer, exact)
// ---------------------------------------------------------------------------
__global__ __launch_bounds__(256) void attn_kv(const u8* __restrict__ sk, const u8* __restrict__ sv,
                                               float* __restrict__ kv){
  const int blk = blockIdx.x;
  const int tid = threadIdx.x;
  const size_t base = ((size_t)(blk >> 3) * 512 + (size_t)(blk & 7) * 64) * 256;
  __shared__ u8 kS[64][256];
  __shared__ u8 vS[64][256];
  const uint32_t* K32 = (const uint32_t*)(sk + base);
  const uint32_t* V32 = (const uint32_t*)(sv + base);
  uint32_t* kS32 = (uint32_t*)&kS[0][0];
  uint32_t* vS32 = (uint32_t*)&vS[0][0];
  #pragma unroll
  for (int i = 0; i < 16; ++i){ kS32[i*256+tid] = K32[i*256+tid]; vS32[i*256+tid] = V32[i*256+tid]; }
  __syncthreads();
  const int d0 = (tid >> 4) << 2, e0 = (tid & 15) << 2;
  int acc[4][4] = {};
  for (int n = 0; n < 256; ++n){
    int k_[4], v_[4];
    #pragma unroll
    for (int i = 0; i < 4; ++i) k_[i] = kS[d0+i][n];
    #pragma unroll
    for (int j = 0; j < 4; ++j) v_[j] = vS[e0+j][n];
    #pragma unroll
    for (int i = 0; i < 4; ++i)
      #pragma unroll
      for (int j = 0; j < 4; ++j) acc[i][j] += k_[i]*v_[j];
  }
  float* KV = kv + (size_t)blk * 4096;
  #pragma unroll
  for (int i = 0; i < 4; ++i)
    #pragma unroll
    for (int j = 0; j < 4; ++j) KV[(d0+i)*64 + e0+j] = (float)acc[i][j];
}

__global__ __launch_bounds__(256) void attn_qkv(const u8* __restrict__ sq, const float* __restrict__ kv,
                                                float* __restrict__ attn){
  const int blk = blockIdx.x;
  const int tid = threadIdx.x;
  const size_t base = ((size_t)(blk >> 3) * 512 + (size_t)(blk & 7) * 64) * 256;
  __shared__ u8 qS[64][256];
  __shared__ float kvS[64][64];
  const uint32_t* Q32 = (const uint32_t*)(sq + base);
  uint32_t* qS32 = (uint32_t*)&qS[0][0];
  const float* KV = kv + (size_t)blk * 4096;
  #pragma unroll
  for (int i = 0; i < 16; ++i){
    qS32[i*256+tid] = Q32[i*256+tid];
    (&kvS[0][0])[i*256+tid] = KV[i*256+tid];
  }
  __syncthreads();
  const int n = tid;
  float acc[64];
  #pragma unroll
  for (int e = 0; e < 64; ++e) acc[e] = 0.0f;
  for (int d = 0; d < 64; ++d){
    float qf = (float)qS[d][n];
    #pragma unroll
    for (int e = 0; e < 64; ++e) acc[e] = fmaf(qf, kvS[d][e], acc[e]);
  }
  float* A = attn + base;
  #pragma unroll
  for (int e = 0; e < 64; ++e) A[(size_t)e*256 + n] = acc[e]*0.125f;
}

// ---------------------------------------------------------------------------
extern "C" void kernel_launch(void* const* d_in, const int* in_sizes, int n_in,
                              void* d_out, int out_size, void* d_ws, size_t ws_size,
                              hipStream_t stream){
  const float* x       = (const float*)d_in[0];
  const float* Wb[4]   = {(const float*)d_in[1], (const float*)d_in[4], (const float*)d_in[7], (const float*)d_in[10]};
  const float* Gm[4]   = {(const float*)d_in[2], (const float*)d_in[5], (const float*)d_in[8], (const float*)d_in[12]};
  const float* Bt[4]   = {(const float*)d_in[3], (const float*)d_in[6], (const float*)d_in[9], (const float*)d_in[13]};
  // d_in[11] = proj_b: cancels exactly inside training-mode BN -> unused.

  char* p = (char*)d_ws;
  float* yA   = (float*)p;            p += 33554432;   // conv out; aliased: Gpart (f64) early, Gspart (f32) pre-proj
  u8* s_q     = (u8*)p;               p += 8388608;
  u8* s_k     = (u8*)p;               p += 8388608;
  u8* s_v     = (u8*)p;               p += 8388608;
  u8* s_at    = (u8*)p;               p += 8388608;
  float* XT32 = (float*)p;
  u8* sT      = (u8*)p;               p += 33554432;   // sT aliases XT32 (XT32 dead before proj)
  ushort* Whl = (ushort*)p;           p += 4194304;    // [4 mats][hi 262144 | lo 262144] ushorts
  float* kvb  = (float*)p;            p += 8388608;
  double* G   = (double*)p;           p += 2097152;
  float* Gs   = (float*)p;            p += 1048576;
  double* M   = (double*)p;           p += 2097152;
  double* colsumX = (double*)p;       p += 4096;
  double* colsumS = (double*)p;       p += 4096;
  double* xnorm   = (double*)p;       p += 131072;
  double* snorm   = (double*)p;       p += 131072;
  double* wn      = (double*)p;       p += 16384;      // [4][512]
  double* stats   = (double*)p;       p += 32768;      // [4][1024]
  int*    cnt     = (int*)p;          p += 256;
  uint*   lists   = (uint*)p;         p += 4*CAP*4;    // [4][CAP] uints
  const size_t NEED = (size_t)(p - (char*)d_ws);

  double* Gpart  = (double*)yA;     // 16 x 512x512 fp64 = 33.5 MB (yA dead until first fgemm)
  float*  Gspart = (float*)yA;      // 16 x 512x512 f32  = 16.8 MB (yA dead during proj-gram)

  if (ws_size < NEED){
    guard_fill<<<(out_size+255)/256, 256, 0, stream>>>((float*)d_out, out_size);
    return;
  }

  const double K0 = 4.0e-5;   // qkv fast-path bound const (~6x expected-max err)
  const double K1 = 4.0e-5;   // proj (B exact 0/1)

  hipMemsetAsync(cnt, 0, 256, stream);

  for (int i=0;i<4;++i){
    w_split<<<1024, 256, 0, stream>>>(Wb[i], Whl + (size_t)i*524288, Whl + (size_t)i*524288 + 262144);
    wnorm_k<<<512, 256, 0, stream>>>(Wb[i], wn + i*512);
  }
  xtrans32<<<dim3(4,8,64), 256, 0, stream>>>(x, XT32);
  colsum_k<float><<<512, 256, 0, stream>>>(x, colsumX);
  norm_k2<float><<<256, 256, 0, stream>>>(x, xnorm);
  gramx2t<<<dim3(36,16), 256, 0, stream>>>(x, Gpart);
  greduce64<<<1024, 256, 0, stream>>>(Gpart, G);

  u8* sOut[3] = {s_q, s_k, s_v};
  for (int i=0;i<3;++i){
    hipMemsetAsync(M, 0, 2097152, stream);
    mgemm<double><<<dim3(8,8,4), 256, 0, stream>>>(Wb[i], G, M);
    finalize_stats<<<512, 256, 0, stream>>>(Wb[i], M, colsumX, Gm[i], Bt[i], stats + i*1024);
    fgemm<0><<<dim3(2,4,64), 256, 0, stream>>>(Whl + (size_t)i*524288, Whl + (size_t)i*524288 + 262144,
                                               XT32, yA);
    bn_lif_flag<0><<<8192, 256, 0, stream>>>(yA, stats + i*1024, wn + i*512, xnorm, K0,
                                             sOut[i], lists + (size_t)i*CAP, cnt + i);
    recompute<0><<<512, 256, 0, stream>>>(lists + (size_t)i*CAP, cnt + i, Wb[i], XT32, stats + i*1024, sOut[i]);
  }

  attn_kv<<<512, 256, 0, stream>>>(s_k, s_v, kvb);
  attn_qkv<<<512, 256, 0, stream>>>(s_q, kvb, yA);
  lif_kernel<<<8192, 256, 0, stream>>>(yA, 0.5, s_at);

  u8_trans<<<dim3(4,8,64), 256, 0, stream>>>(s_at, sT);
  colsum_k<u8><<<512, 256, 0, stream>>>(s_at, colsumS);
  norm_k2<u8><<<256, 256, 0, stream>>>(s_at, snorm);
  sgram<<<dim3(4,4,16), 256, 0, stream>>>(s_at, Gspart);
  greduceS<<<1024, 256, 0, stream>>>(Gspart, Gs);

  hipMemsetAsync(M, 0, 2097152, stream);
  mgemm<float><<<dim3(8,8,4), 256, 0, stream>>>(Wb[3], Gs, M);
  finalize_stats<<<512, 256, 0, stream>>>(Wb[3], M, colsumS, Gm[3], Bt[3], stats + 3*1024);
  fgemm<1><<<dim3(2,4,64), 256, 0, stream>>>(Whl + (size_t)3*524288, Whl + (size_t)3*524288 + 262144,
                                             sT, yA);
  bn_lif_flag<1><<<8192, 256, 0, stream>>>(yA, stats + 3*1024, wn + 3*512, snorm, K1,
                                           d_out, lists + (size_t)3*CAP, cnt + 3);
  recompute<1><<<512, 256, 0, stream>>>(lists + (size_t)3*CAP, cnt + 3, Wb[3], sT, stats + 3*1024, d_out);
}